// Round 6
// baseline (115.832 us; speedup 1.0000x reference)
//
#include <hip/hip_runtime.h>

// CrossAttention: x[4,2048,512], context[4,2048,512], Wq/Wk/Wv[512,512], Wo[512,512], bo[512]
// out = softmax(QK^T/sqrt(64)) V -> @Wo + bo.  All-bf16 MFMA pipeline, fp32 accum.
// R6: launch_bounds(256,4) on GEMMs (3 blocks/CU co-resident), flash depth-2 prefetch
//     with 3 LDS buffers + counted vmcnt(2) (T4: never drain to 0 mid-loop).

typedef short bf16x8 __attribute__((ext_vector_type(8)));
typedef float f32x4 __attribute__((ext_vector_type(4)));
typedef float f32x16 __attribute__((ext_vector_type(16)));
typedef unsigned int u32x4 __attribute__((ext_vector_type(4)));

#define NB 4
#define NN 2048
#define QD 512
#define DH 64
// log2(e)/sqrt(DH): folded into Q so softmax runs in exp2 domain
#define QSCALE 0.18033688011112042f

__device__ __forceinline__ unsigned short f2bf(float f) {
  unsigned u = __float_as_uint(f);
  unsigned r = (u + 0x7fffu + ((u >> 16) & 1u)) >> 16;
  return (unsigned short)r;
}

__device__ __forceinline__ unsigned cvtpk(float a, float b) {
  unsigned r;
  asm("v_cvt_pk_bf16_f32 %0, %1, %2" : "=v"(r) : "v"(a), "v"(b));
  return r;
}

__device__ __forceinline__ void pl32swap(unsigned& a, unsigned& b) {
  asm("v_permlane32_swap_b32 %0, %1" : "+v"(a), "+v"(b));
}

__device__ __forceinline__ void gload16(const void* g, void* l) {
  __builtin_amdgcn_global_load_lds((const __attribute__((address_space(1))) unsigned int*)g,
                                   (__attribute__((address_space(3))) unsigned int*)l, 16, 0, 0);
}

// ---------------- transpose weights to [col][k] bf16 ----------------
__global__ __launch_bounds__(256) void cvt_weights(const float* __restrict__ Wq, const float* __restrict__ Wk,
                                                   const float* __restrict__ Wv, const float* __restrict__ Wo,
                                                   unsigned short* __restrict__ wqt, unsigned short* __restrict__ wkt,
                                                   unsigned short* __restrict__ wvt, unsigned short* __restrict__ wot) {
  __shared__ float t[32][33];
  const float* W = blockIdx.z == 0 ? Wq : blockIdx.z == 1 ? Wk : blockIdx.z == 2 ? Wv : Wo;
  unsigned short* O = blockIdx.z == 0 ? wqt : blockIdx.z == 1 ? wkt : blockIdx.z == 2 ? wvt : wot;
  int c0 = blockIdx.x * 32, k0 = blockIdx.y * 32;
  int tx = threadIdx.x, ty = threadIdx.y;  // 32 x 8
#pragma unroll
  for (int j = 0; j < 4; j++) t[ty + 8 * j][tx] = W[(k0 + ty + 8 * j) * QD + c0 + tx];
  __syncthreads();
#pragma unroll
  for (int j = 0; j < 4; j++) O[(c0 + ty + 8 * j) * QD + k0 + tx] = f2bf(t[tx][ty + 8 * j]);
}

// ---------------- fused QKV projection ----------------
// grid (64 rowblk, 4 colblk, 3 z) = 768 blocks -> 3 blocks/CU co-resident at (256,4).
__global__ __launch_bounds__(256, 4) void qkv_gemm(const float* __restrict__ x, const float* __restrict__ ctx,
                                                   const unsigned short* __restrict__ wqt,
                                                   const unsigned short* __restrict__ wkt,
                                                   const unsigned short* __restrict__ wvt,
                                                   unsigned short* __restrict__ q_ws,
                                                   unsigned short* __restrict__ k_ws,
                                                   unsigned short* __restrict__ v_ws) {
  __shared__ __align__(16) unsigned short sA[128 * 64];
  __shared__ __align__(16) unsigned short sB[128 * 64];
  const int z = blockIdx.z;
  const float* A = (z == 0) ? x : ctx;
  const unsigned short* Bt = (z == 0) ? wqt : (z == 1) ? wkt : wvt;
  const int lane = threadIdx.x & 63, wid = threadIdx.x >> 6;
  const int lo = lane & 15, hi = lane >> 4;
  const int wm = wid >> 1, wn = wid & 1;
  const int r0 = blockIdx.x * 128, c0 = blockIdx.y * 128;
  const int r8 = lane >> 3, c8l = lane & 7;
  f32x4 acc[4][4] = {};
  for (int k0 = 0; k0 < QD; k0 += 64) {
    __syncthreads();
#pragma unroll
    for (int i = 0; i < 4; i++) {
      int id = i * 256 + threadIdx.x;
      int row = id >> 3, ks = id & 7;
      const float* ap = &A[(r0 + row) * QD + k0 + ks * 8];
      float4 a = *(const float4*)ap;
      float4 b = *(const float4*)(ap + 4);
      u32x4 w = {cvtpk(a.x, a.y), cvtpk(a.z, a.w), cvtpk(b.x, b.y), cvtpk(b.z, b.w)};
      *(u32x4*)((char*)sA + id * 16) = w;
      int chunk = wid * 4 + i;
      int brow = chunk * 8 + r8;
      gload16(&Bt[(c0 + brow) * QD + k0 + c8l * 8], (char*)sB + chunk * 1024);
    }
    __syncthreads();
#pragma unroll
    for (int kk = 0; kk < 2; kk++) {
      bf16x8 af[4], bfr[4];
#pragma unroll
      for (int t = 0; t < 4; t++) af[t] = *(const bf16x8*)&sA[(wm * 64 + t * 16 + lo) * 64 + (kk * 4 + hi) * 8];
#pragma unroll
      for (int u = 0; u < 4; u++) bfr[u] = *(const bf16x8*)&sB[(wn * 64 + u * 16 + lo) * 64 + (kk * 4 + hi) * 8];
#pragma unroll
      for (int t = 0; t < 4; t++)
#pragma unroll
        for (int u = 0; u < 4; u++)
          acc[t][u] = __builtin_amdgcn_mfma_f32_16x16x32_bf16(af[t], bfr[u], acc[t][u], 0, 0, 0);
    }
  }
  const float outscale = (z == 0) ? QSCALE : 1.0f;
  unsigned short* Cq = (z == 0) ? q_ws : k_ws;
#pragma unroll
  for (int t = 0; t < 4; t++)
#pragma unroll
    for (int u = 0; u < 4; u++)
#pragma unroll
      for (int ri = 0; ri < 4; ri++) {
        int r = r0 + wm * 64 + t * 16 + hi * 4 + ri;
        int c = c0 + wn * 64 + u * 16 + lo;
        float v = acc[t][u][ri] * outscale;
        int b = r >> 11, n = r & 2047, h = c >> 6, d = c & 63;
        if (z == 2)
          v_ws[(((b << 3) | h) * DH + d) * NN + n] = f2bf(v);
        else
          Cq[(((b << 3) | h) * NN + n) * DH + d] = f2bf(v);
      }
}

// ---------------- flash attention: 8-wave, KVBLK=64, depth-2 prefetch, split-KV ----------------
// grid (32 bh, 8 qblk, 2 kv-half), 512 thr = 8 waves. Wave owns 32 q rows (q = lane&31);
// lanes L, L^32 split each q's 64 key-scores per tile. 16 iters of 64 keys.
// 3 LDS buffers; stage(it+2) in flight; wait vmcnt(2) (stage(it) done, stage(it+1) outstanding).
__global__ __launch_bounds__(512, 4) void flash_attn(const unsigned short* __restrict__ Q,
                                                     const unsigned short* __restrict__ K,
                                                     const unsigned short* __restrict__ Vt,
                                                     unsigned short* __restrict__ po,
                                                     float* __restrict__ pml) {
  __shared__ __align__(16) char sKV[3][16384];  // [buf][K 64x64 | V^T 64x64]
  const int tid = threadIdx.x;
  const int lane = tid & 63, wid = tid >> 6;
  const int l31 = lane & 31, hi = lane >> 5;
  const int bh = blockIdx.x, half = blockIdx.z;
  const int bhK = bh * NN, bhV = bh * DH;
  const int kv0 = half * (NN / 2);
  const int qrow = blockIdx.y * 256 + wid * 32 + l31;
  po += half * (32 * 2048 * 64);
  pml += half * (32 * 2048);

  // Q fragments (B-operand): col=q(=l31), k(d) = ks*16 + hi*8 + j
  bf16x8 qf[4];
#pragma unroll
  for (int ks = 0; ks < 4; ks++)
    qf[ks] = *(const bf16x8*)&Q[(bhK + qrow) * DH + ks * 16 + hi * 8];

  // staging role: thread t handles chunk t of K region and chunk t of V region
  const int row_s = tid >> 3, slot_s = tid & 7;
  const int swz = (slot_s ^ (row_s & 7)) * 8;

#define STAGE(J0, BUF)                                                     \
  do {                                                                     \
    char* b_ = (char*)sKV[BUF];                                            \
    gload16(&K[(bhK + (J0) + row_s) * DH + swz], b_ + wid * 1024);         \
    gload16(&Vt[(bhV + row_s) * NN + (J0) + swz], b_ + 8192 + wid * 1024); \
  } while (0)

  float l = 0.f;
  f32x16 o[2] = {};

  STAGE(kv0, 0);
  STAGE(kv0 + 64, 1);

  for (int it = 0; it < 16; ++it) {
    // stage(it) must be complete; stage(it+1) may stay in flight (T4: counted, never 0 mid-loop)
    if (it < 15) {
      asm volatile("s_waitcnt vmcnt(2)" ::: "memory");
    } else {
      asm volatile("s_waitcnt vmcnt(0)" ::: "memory");
    }
    __builtin_amdgcn_s_barrier();    // all waves' stage(it) done; buf[(it+2)%3] fully consumed
    __builtin_amdgcn_sched_barrier(0);
    if (it + 2 < 16) STAGE(kv0 + (it + 2) * 64, (it + 2) % 3);
    const char* buf = (const char*)sKV[it % 3];

    // S^T[key][q] = K . Q^T  (2 key-tiles of 32, 4 d-slices of 16)
    f32x16 st[2] = {};
    __builtin_amdgcn_s_setprio(1);
#pragma unroll
    for (int g = 0; g < 2; g++)
#pragma unroll
      for (int ks = 0; ks < 4; ks++) {
        bf16x8 kf = *(const bf16x8*)(buf + (g * 32 + l31) * 128 + (((ks * 2 + hi) ^ (l31 & 7)) << 4));
        st[g] = __builtin_amdgcn_mfma_f32_32x32x16_bf16(kf, qf[ks], st[g], 0, 0, 0);
      }
    __builtin_amdgcn_s_setprio(0);

    // fixed-max softmax (m = 0; shift-invariant, logits hard-bounded far below fp32 overflow)
#pragma unroll
    for (int g = 0; g < 2; g++)
#pragma unroll
      for (int c = 0; c < 16; c++) st[g][c] = __builtin_amdgcn_exp2f(st[g][c]);
    float s8[8];
#pragma unroll
    for (int c = 0; c < 8; c++) s8[c] = (st[0][c] + st[0][c + 8]) + (st[1][c] + st[1][c + 8]);
#pragma unroll
    for (int w = 4; w >= 1; w >>= 1)
#pragma unroll
      for (int c = 0; c < 4; c++)
        if (c < w) s8[c] += s8[c + w];
    l += s8[0] + __shfl_xor(s8[0], 32);

    // P -> bf16 B-fragments (verified mapping):
    // (w0,w2)=swap(pk(c0,c1),pk(c4,c5)); (w1,w3)=swap(pk(c2,c3),pk(c6,c7)); cb=s*8.
    bf16x8 pf[2][2];
#pragma unroll
    for (int g = 0; g < 2; g++)
#pragma unroll
      for (int s = 0; s < 2; s++) {
        const int cb = s * 8;
        unsigned a0 = cvtpk(st[g][cb + 0], st[g][cb + 1]);
        unsigned a1 = cvtpk(st[g][cb + 2], st[g][cb + 3]);
        unsigned b0 = cvtpk(st[g][cb + 4], st[g][cb + 5]);
        unsigned b1 = cvtpk(st[g][cb + 6], st[g][cb + 7]);
        pl32swap(a0, b0);
        pl32swap(a1, b1);
        union { unsigned u[4]; bf16x8 v; } pu;
        pu.u[0] = a0; pu.u[1] = a1; pu.u[2] = b0; pu.u[3] = b1;
        pf[g][s] = pu.v;
      }

    // O^T[d][q] += V^T . P^T  (2 d-tiles x 2 key-tiles x 2 slices)
    __builtin_amdgcn_s_setprio(1);
#pragma unroll
    for (int dt = 0; dt < 2; dt++)
#pragma unroll
      for (int g = 0; g < 2; g++)
#pragma unroll
        for (int s = 0; s < 2; s++) {
          int row = dt * 32 + l31;
          bf16x8 vf = *(const bf16x8*)(buf + 8192 + row * 128 + (((g * 4 + s * 2 + hi) ^ (row & 7)) << 4));
          o[dt] = __builtin_amdgcn_mfma_f32_32x32x16_bf16(vf, pf[g][s], o[dt], 0, 0, 0);
        }
    __builtin_amdgcn_s_setprio(0);
  }
#undef STAGE

  // store partial: o normalized by own l (bf16); l (f32)
  float inv = 1.f / l;
  const int rbase = (bh * 2048 + qrow) * 64;
#pragma unroll
  for (int dt = 0; dt < 2; dt++)
#pragma unroll
    for (int cg = 0; cg < 4; cg++) {
      ushort4 w;
      w.x = f2bf(o[dt][cg * 4 + 0] * inv);
      w.y = f2bf(o[dt][cg * 4 + 1] * inv);
      w.z = f2bf(o[dt][cg * 4 + 2] * inv);
      w.w = f2bf(o[dt][cg * 4 + 3] * inv);
      int d0 = dt * 32 + cg * 8 + hi * 4;
      *(ushort4*)&po[rbase + d0] = w;
    }
  if (hi == 0) pml[bh * 2048 + qrow] = l;
}

// ---------------- output projection with fused split-KV combine ----------------
// A[r][k0-slice] built in staging: weighted sum of po0/po1 (weights l0,l1 per (b,h,n)).
// 128x64 tiles -> grid (64, 8). Each k0 covers exactly one head h = k0>>6.
__global__ __launch_bounds__(256, 4) void out_gemm(const unsigned short* __restrict__ po,
                                                   const float* __restrict__ pml,
                                                   const unsigned short* __restrict__ Bt,
                                                   float* __restrict__ out,
                                                   const float* __restrict__ bias) {
  __shared__ __align__(16) unsigned short sA[128 * 64];
  __shared__ __align__(16) unsigned short sB[64 * 64];
  const unsigned short* po1 = po + 32 * 2048 * 64;
  const float* pml1 = pml + 32 * 2048;
  const int lane = threadIdx.x & 63, wid = threadIdx.x >> 6;
  const int lo = lane & 15, hi = lane >> 4;
  const int wm = wid >> 1, wn = wid & 1;
  const int r0 = blockIdx.x * 128, c0 = blockIdx.y * 64;
  const int r8 = lane >> 3, c8l = lane & 7;
  f32x4 acc[4][2] = {};
  for (int k0 = 0; k0 < QD; k0 += 64) {
    __syncthreads();
    const int h = k0 >> 6;
#pragma unroll
    for (int i = 0; i < 4; i++) {
      int id = i * 256 + threadIdx.x;
      int row = id >> 3, slot = id & 7;
      int r = r0 + row, b = r >> 11, n = r & 2047;
      int pr = ((b << 3) | h) * NN + n;
      float la = pml[pr], lb = pml1[pr];
      float s = __builtin_amdgcn_rcpf(la + lb);
      float wa = la * s, wb = lb * s;
      u32x4 A0 = *(const u32x4*)&po[pr * 64 + slot * 8];
      u32x4 A1 = *(const u32x4*)&po1[pr * 64 + slot * 8];
      u32x4 res;
#pragma unroll
      for (int j = 0; j < 4; j++) {
        float a_lo = __uint_as_float(A0[j] << 16), a_hi = __uint_as_float(A0[j] & 0xffff0000u);
        float b_lo = __uint_as_float(A1[j] << 16), b_hi = __uint_as_float(A1[j] & 0xffff0000u);
        res[j] = cvtpk(a_lo * wa + b_lo * wb, a_hi * wa + b_hi * wb);
      }
      *(u32x4*)((char*)sA + id * 16) = res;
    }
#pragma unroll
    for (int i = 0; i < 2; i++) {
      int chunk = wid * 2 + i;
      int row = chunk * 8 + r8;
      gload16(&Bt[(c0 + row) * QD + k0 + c8l * 8], (char*)sB + chunk * 1024);
    }
    __syncthreads();
#pragma unroll
    for (int kk = 0; kk < 2; kk++) {
      bf16x8 af[4], bfr[2];
#pragma unroll
      for (int t = 0; t < 4; t++) af[t] = *(const bf16x8*)&sA[(wm * 64 + t * 16 + lo) * 64 + (kk * 4 + hi) * 8];
#pragma unroll
      for (int u = 0; u < 2; u++) bfr[u] = *(const bf16x8*)&sB[(wn * 32 + u * 16 + lo) * 64 + (kk * 4 + hi) * 8];
#pragma unroll
      for (int t = 0; t < 4; t++)
#pragma unroll
        for (int u = 0; u < 2; u++)
          acc[t][u] = __builtin_amdgcn_mfma_f32_16x16x32_bf16(af[t], bfr[u], acc[t][u], 0, 0, 0);
    }
  }
#pragma unroll
  for (int t = 0; t < 4; t++)
#pragma unroll
    for (int u = 0; u < 2; u++)
#pragma unroll
      for (int ri = 0; ri < 4; ri++) {
        int r = r0 + wm * 64 + t * 16 + hi * 4 + ri;
        int c = c0 + wn * 32 + u * 16 + lo;
        out[r * QD + c] = acc[t][u][ri] + bias[c];
      }
}

extern "C" void kernel_launch(void* const* d_in, const int* in_sizes, int n_in,
                              void* d_out, int out_size, void* d_ws, size_t ws_size,
                              hipStream_t stream) {
  const float* x   = (const float*)d_in[0];
  const float* ctx = (const float*)d_in[1];
  const float* Wq  = (const float*)d_in[2];
  const float* Wk  = (const float*)d_in[3];
  const float* Wv  = (const float*)d_in[4];
  const float* Wo  = (const float*)d_in[5];
  const float* bo  = (const float*)d_in[6];
  char* ws = (char*)d_ws;

  unsigned short* wqt  = (unsigned short*)(ws);              // 512 KB each
  unsigned short* wkt  = (unsigned short*)(ws + 524288);
  unsigned short* wvt  = (unsigned short*)(ws + 1048576);
  unsigned short* wot  = (unsigned short*)(ws + 1572864);
  unsigned short* q_ws = (unsigned short*)(ws + 2097152);    // 8 MB, [bh][n][64]
  unsigned short* k_ws = (unsigned short*)(ws + 10485760);   // 8 MB, [bh][m][64]
  unsigned short* v_ws = (unsigned short*)(ws + 18874368);   // 8 MB, [bh][64][m]
  unsigned short* po   = (unsigned short*)(ws + 27262976);   // 16 MB, [half][bh][q][64]
  float*          pml  = (float*)(ws + 44040192);            // 512 KB, [half][bh*2048+q]
  float* out = (float*)d_out;

  cvt_weights<<<dim3(16, 16, 4), dim3(32, 8), 0, stream>>>(Wq, Wk, Wv, Wo, wqt, wkt, wvt, wot);

  qkv_gemm<<<dim3(64, 4, 3), 256, 0, stream>>>(x, ctx, wqt, wkt, wvt, q_ws, k_ws, v_ws);

  flash_attn<<<dim3(32, 8, 2), 512, 0, stream>>>(q_ws, k_ws, v_ws, po, pml);

  out_gemm<<<dim3(64, 8), 256, 0, stream>>>(po, pml, wot, out, bo);
}

// Round 7
// 112.151 us; speedup vs baseline: 1.0328x; 1.0328x over previous
//
#include <hip/hip_runtime.h>

// CrossAttention: x[4,2048,512], context[4,2048,512], Wq/Wk/Wv[512,512], Wo[512,512], bo[512]
// out = softmax(QK^T/sqrt(64)) V -> @Wo + bo.  All-bf16 MFMA pipeline, fp32 accum.
// R7: qkv_gemm rebuilt as pure global_load_lds double-buffered GEMM (prefetch STAGE(k+1)
//     before compute(k), bf16 A via cvt_inputs); flash/out reverted to proven R5 bodies.

typedef short bf16x8 __attribute__((ext_vector_type(8)));
typedef float f32x4 __attribute__((ext_vector_type(4)));
typedef float f32x16 __attribute__((ext_vector_type(16)));
typedef unsigned int u32x4 __attribute__((ext_vector_type(4)));

#define NB 4
#define NN 2048
#define QD 512
#define DH 64
// log2(e)/sqrt(DH): folded into Q so softmax runs in exp2 domain
#define QSCALE 0.18033688011112042f

__device__ __forceinline__ unsigned short f2bf(float f) {
  unsigned u = __float_as_uint(f);
  unsigned r = (u + 0x7fffu + ((u >> 16) & 1u)) >> 16;
  return (unsigned short)r;
}

__device__ __forceinline__ unsigned cvtpk(float a, float b) {
  unsigned r;
  asm("v_cvt_pk_bf16_f32 %0, %1, %2" : "=v"(r) : "v"(a), "v"(b));
  return r;
}

__device__ __forceinline__ void pl32swap(unsigned& a, unsigned& b) {
  asm("v_permlane32_swap_b32 %0, %1" : "+v"(a), "+v"(b));
}

__device__ __forceinline__ void gload16(const void* g, void* l) {
  __builtin_amdgcn_global_load_lds((const __attribute__((address_space(1))) unsigned int*)g,
                                   (__attribute__((address_space(3))) unsigned int*)l, 16, 0, 0);
}

// ---------------- convert x / context to bf16 ----------------
__global__ __launch_bounds__(256) void cvt_inputs(const float* __restrict__ x,
                                                  const float* __restrict__ ctx,
                                                  unsigned short* __restrict__ xb,
                                                  unsigned short* __restrict__ cb) {
  int i = blockIdx.x * 256 + threadIdx.x;
  const int total = (NB * NN * QD) / 4;
  if (i < total) {
    float4 v = ((const float4*)x)[i];
    ushort4 o;
    o.x = f2bf(v.x); o.y = f2bf(v.y); o.z = f2bf(v.z); o.w = f2bf(v.w);
    ((ushort4*)xb)[i] = o;
    float4 w = ((const float4*)ctx)[i];
    ushort4 p;
    p.x = f2bf(w.x); p.y = f2bf(w.y); p.z = f2bf(w.z); p.w = f2bf(w.w);
    ((ushort4*)cb)[i] = p;
  }
}

// ---------------- transpose weights to [col][k] bf16 ----------------
__global__ __launch_bounds__(256) void cvt_weights(const float* __restrict__ Wq, const float* __restrict__ Wk,
                                                   const float* __restrict__ Wv, const float* __restrict__ Wo,
                                                   unsigned short* __restrict__ wqt, unsigned short* __restrict__ wkt,
                                                   unsigned short* __restrict__ wvt, unsigned short* __restrict__ wot) {
  __shared__ float t[32][33];
  const float* W = blockIdx.z == 0 ? Wq : blockIdx.z == 1 ? Wk : blockIdx.z == 2 ? Wv : Wo;
  unsigned short* O = blockIdx.z == 0 ? wqt : blockIdx.z == 1 ? wkt : blockIdx.z == 2 ? wvt : wot;
  int c0 = blockIdx.x * 32, k0 = blockIdx.y * 32;
  int tx = threadIdx.x, ty = threadIdx.y;  // 32 x 8
#pragma unroll
  for (int j = 0; j < 4; j++) t[ty + 8 * j][tx] = W[(k0 + ty + 8 * j) * QD + c0 + tx];
  __syncthreads();
#pragma unroll
  for (int j = 0; j < 4; j++) O[(c0 + ty + 8 * j) * QD + k0 + tx] = f2bf(t[tx][ty + 8 * j]);
}

// ---------------- fused QKV projection: gload dbuf, prefetch-before-compute ----------------
// grid (4 colblk, 64 rowblk, 3 z): consecutive blocks share the A-panel (L2 locality).
// 128x128 tile, BK=64, 4 waves (2x2). LDS 2 x (16KB A + 16KB B) = 64 KB.
__global__ __launch_bounds__(256, 2) void qkv_gemm(const unsigned short* __restrict__ xb,
                                                   const unsigned short* __restrict__ cb,
                                                   const unsigned short* __restrict__ wqt,
                                                   const unsigned short* __restrict__ wkt,
                                                   const unsigned short* __restrict__ wvt,
                                                   unsigned short* __restrict__ q_ws,
                                                   unsigned short* __restrict__ k_ws,
                                                   unsigned short* __restrict__ v_ws) {
  __shared__ __align__(16) char sAB[2][32768];  // [buf][A 128x64 | B 128x64]
  const int z = blockIdx.z;
  const unsigned short* A = (z == 0) ? xb : cb;
  const unsigned short* Bt = (z == 0) ? wqt : (z == 1) ? wkt : wvt;
  const int lane = threadIdx.x & 63, wid = threadIdx.x >> 6;
  const int lo = lane & 15, hi = lane >> 4;
  const int wm = wid >> 1, wn = wid & 1;
  const int c0 = blockIdx.x * 128, r0 = blockIdx.y * 128;
  const int r8 = lane >> 3, c8l = lane & 7;

#define STAGEQ(K0, BUF)                                                      \
  do {                                                                       \
    char* b_ = sAB[BUF];                                                     \
    _Pragma("unroll") for (int i_ = 0; i_ < 4; ++i_) {                       \
      int chunk_ = wid * 4 + i_;                                             \
      int row_ = chunk_ * 8 + r8;                                            \
      gload16(&A[(r0 + row_) * QD + (K0) + c8l * 8], b_ + chunk_ * 1024);    \
      gload16(&Bt[(c0 + row_) * QD + (K0) + c8l * 8],                        \
              b_ + 16384 + chunk_ * 1024);                                   \
    }                                                                        \
  } while (0)

  f32x4 acc[4][4] = {};
  STAGEQ(0, 0);
  for (int ks = 0; ks < 8; ++ks) {
    asm volatile("s_waitcnt vmcnt(0)" ::: "memory");  // own stage(ks) writes landed
    __builtin_amdgcn_s_barrier();                      // all stage(ks) done; buf(ks^1) consumed
    __builtin_amdgcn_sched_barrier(0);
    if (ks + 1 < 8) STAGEQ((ks + 1) * 64, (ks + 1) & 1);
    const unsigned short* sA = (const unsigned short*)sAB[ks & 1];
    const unsigned short* sB = sA + 8192;
#pragma unroll
    for (int kk = 0; kk < 2; kk++) {
      bf16x8 af[4], bfr[4];
#pragma unroll
      for (int t = 0; t < 4; t++) af[t] = *(const bf16x8*)&sA[(wm * 64 + t * 16 + lo) * 64 + (kk * 4 + hi) * 8];
#pragma unroll
      for (int u = 0; u < 4; u++) bfr[u] = *(const bf16x8*)&sB[(wn * 64 + u * 16 + lo) * 64 + (kk * 4 + hi) * 8];
#pragma unroll
      for (int t = 0; t < 4; t++)
#pragma unroll
        for (int u = 0; u < 4; u++)
          acc[t][u] = __builtin_amdgcn_mfma_f32_16x16x32_bf16(af[t], bfr[u], acc[t][u], 0, 0, 0);
    }
  }
#undef STAGEQ
  const float outscale = (z == 0) ? QSCALE : 1.0f;
  unsigned short* Cq = (z == 0) ? q_ws : k_ws;
#pragma unroll
  for (int t = 0; t < 4; t++)
#pragma unroll
    for (int u = 0; u < 4; u++)
#pragma unroll
      for (int ri = 0; ri < 4; ri++) {
        int r = r0 + wm * 64 + t * 16 + hi * 4 + ri;
        int c = c0 + wn * 64 + u * 16 + lo;
        float v = acc[t][u][ri] * outscale;
        int b = r >> 11, n = r & 2047, h = c >> 6, d = c & 63;
        if (z == 2)
          v_ws[(((b << 3) | h) * DH + d) * NN + n] = f2bf(v);
        else
          Cq[(((b << 3) | h) * NN + n) * DH + d] = f2bf(v);
      }
}

// ---------------- flash attention: 8-wave, KVBLK=64, fixed-max, split-KV (R5, proven) ----------------
__global__ __launch_bounds__(512, 4) void flash_attn(const unsigned short* __restrict__ Q,
                                                     const unsigned short* __restrict__ K,
                                                     const unsigned short* __restrict__ Vt,
                                                     unsigned short* __restrict__ po,
                                                     float* __restrict__ pml) {
  __shared__ __align__(16) char sKV[2][16384];  // [buf][K 64x64 | V^T 64x64]
  const int tid = threadIdx.x;
  const int lane = tid & 63, wid = tid >> 6;
  const int l31 = lane & 31, hi = lane >> 5;
  const int bh = blockIdx.x, half = blockIdx.z;
  const int bhK = bh * NN, bhV = bh * DH;
  const int kv0 = half * (NN / 2);
  const int qrow = blockIdx.y * 256 + wid * 32 + l31;
  po += half * (32 * 2048 * 64);
  pml += half * (32 * 2048);

  // Q fragments (B-operand): col=q(=l31), k(d) = ks*16 + hi*8 + j
  bf16x8 qf[4];
#pragma unroll
  for (int ks = 0; ks < 4; ks++)
    qf[ks] = *(const bf16x8*)&Q[(bhK + qrow) * DH + ks * 16 + hi * 8];

  // staging role: thread t handles chunk t of K region and chunk t of V region
  const int row_s = tid >> 3, slot_s = tid & 7;
  const int swz = (slot_s ^ (row_s & 7)) * 8;

#define STAGE(J0, BUF)                                                     \
  do {                                                                     \
    char* b_ = (char*)sKV[BUF];                                            \
    gload16(&K[(bhK + (J0) + row_s) * DH + swz], b_ + wid * 1024);         \
    gload16(&Vt[(bhV + row_s) * NN + (J0) + swz], b_ + 8192 + wid * 1024); \
  } while (0)

  float l = 0.f;
  f32x16 o[2] = {};

  STAGE(kv0, 0);

  for (int it = 0; it < 16; ++it) {
    asm volatile("s_waitcnt vmcnt(0)" ::: "memory");  // own stage(it) writes done
    __builtin_amdgcn_s_barrier();                      // all stage(it) done; buf(it+1) consumed
    __builtin_amdgcn_sched_barrier(0);
    if (it + 1 < 16) STAGE(kv0 + (it + 1) * 64, (it + 1) & 1);
    const char* buf = (const char*)sKV[it & 1];

    // S^T[key][q] = K . Q^T  (2 key-tiles of 32, 4 d-slices of 16)
    f32x16 st[2] = {};
    __builtin_amdgcn_s_setprio(1);
#pragma unroll
    for (int g = 0; g < 2; g++)
#pragma unroll
      for (int ks = 0; ks < 4; ks++) {
        bf16x8 kf = *(const bf16x8*)(buf + (g * 32 + l31) * 128 + (((ks * 2 + hi) ^ (l31 & 7)) << 4));
        st[g] = __builtin_amdgcn_mfma_f32_32x32x16_bf16(kf, qf[ks], st[g], 0, 0, 0);
      }
    __builtin_amdgcn_s_setprio(0);

    // fixed-max softmax (m = 0; shift-invariant, logits hard-bounded far below fp32 overflow)
#pragma unroll
    for (int g = 0; g < 2; g++)
#pragma unroll
      for (int c = 0; c < 16; c++) st[g][c] = __builtin_amdgcn_exp2f(st[g][c]);
    float s8[8];
#pragma unroll
    for (int c = 0; c < 8; c++) s8[c] = (st[0][c] + st[0][c + 8]) + (st[1][c] + st[1][c + 8]);
#pragma unroll
    for (int w = 4; w >= 1; w >>= 1)
#pragma unroll
      for (int c = 0; c < 4; c++)
        if (c < w) s8[c] += s8[c + w];
    l += s8[0] + __shfl_xor(s8[0], 32);

    // P -> bf16 B-fragments (verified mapping):
    // (w0,w2)=swap(pk(c0,c1),pk(c4,c5)); (w1,w3)=swap(pk(c2,c3),pk(c6,c7)); cb=s*8.
    bf16x8 pf[2][2];
#pragma unroll
    for (int g = 0; g < 2; g++)
#pragma unroll
      for (int s = 0; s < 2; s++) {
        const int cb = s * 8;
        unsigned a0 = cvtpk(st[g][cb + 0], st[g][cb + 1]);
        unsigned a1 = cvtpk(st[g][cb + 2], st[g][cb + 3]);
        unsigned b0 = cvtpk(st[g][cb + 4], st[g][cb + 5]);
        unsigned b1 = cvtpk(st[g][cb + 6], st[g][cb + 7]);
        pl32swap(a0, b0);
        pl32swap(a1, b1);
        union { unsigned u[4]; bf16x8 v; } pu;
        pu.u[0] = a0; pu.u[1] = a1; pu.u[2] = b0; pu.u[3] = b1;
        pf[g][s] = pu.v;
      }

    // O^T[d][q] += V^T . P^T  (2 d-tiles x 2 key-tiles x 2 slices)
    __builtin_amdgcn_s_setprio(1);
#pragma unroll
    for (int dt = 0; dt < 2; dt++)
#pragma unroll
      for (int g = 0; g < 2; g++)
#pragma unroll
        for (int s = 0; s < 2; s++) {
          int row = dt * 32 + l31;
          bf16x8 vf = *(const bf16x8*)(buf + 8192 + row * 128 + (((g * 4 + s * 2 + hi) ^ (row & 7)) << 4));
          o[dt] = __builtin_amdgcn_mfma_f32_32x32x16_bf16(vf, pf[g][s], o[dt], 0, 0, 0);
        }
    __builtin_amdgcn_s_setprio(0);
  }
#undef STAGE

  // store partial: o normalized by own l (bf16); l (f32)
  float inv = 1.f / l;
  const int rbase = (bh * 2048 + qrow) * 64;
#pragma unroll
  for (int dt = 0; dt < 2; dt++)
#pragma unroll
    for (int cg = 0; cg < 4; cg++) {
      ushort4 w;
      w.x = f2bf(o[dt][cg * 4 + 0] * inv);
      w.y = f2bf(o[dt][cg * 4 + 1] * inv);
      w.z = f2bf(o[dt][cg * 4 + 2] * inv);
      w.w = f2bf(o[dt][cg * 4 + 3] * inv);
      int d0 = dt * 32 + cg * 8 + hi * 4;
      *(ushort4*)&po[rbase + d0] = w;
    }
  if (hi == 0) pml[bh * 2048 + qrow] = l;
}

// ---------------- output projection with fused split-KV combine (R5, proven) ----------------
__global__ __launch_bounds__(256, 2) void out_gemm(const unsigned short* __restrict__ po,
                                                   const float* __restrict__ pml,
                                                   const unsigned short* __restrict__ Bt,
                                                   float* __restrict__ out,
                                                   const float* __restrict__ bias) {
  __shared__ __align__(16) unsigned short sA[128 * 64];
  __shared__ __align__(16) unsigned short sB[64 * 64];
  const unsigned short* po1 = po + 32 * 2048 * 64;
  const float* pml1 = pml + 32 * 2048;
  const int lane = threadIdx.x & 63, wid = threadIdx.x >> 6;
  const int lo = lane & 15, hi = lane >> 4;
  const int wm = wid >> 1, wn = wid & 1;
  const int r0 = blockIdx.x * 128, c0 = blockIdx.y * 64;
  const int r8 = lane >> 3, c8l = lane & 7;
  f32x4 acc[4][2] = {};
  for (int k0 = 0; k0 < QD; k0 += 64) {
    __syncthreads();
    const int h = k0 >> 6;
#pragma unroll
    for (int i = 0; i < 4; i++) {
      int id = i * 256 + threadIdx.x;
      int row = id >> 3, slot = id & 7;
      int r = r0 + row, b = r >> 11, n = r & 2047;
      int pr = ((b << 3) | h) * NN + n;
      float la = pml[pr], lb = pml1[pr];
      float s = __builtin_amdgcn_rcpf(la + lb);
      float wa = la * s, wb = lb * s;
      u32x4 A0 = *(const u32x4*)&po[pr * 64 + slot * 8];
      u32x4 A1 = *(const u32x4*)&po1[pr * 64 + slot * 8];
      u32x4 res;
#pragma unroll
      for (int j = 0; j < 4; j++) {
        float a_lo = __uint_as_float(A0[j] << 16), a_hi = __uint_as_float(A0[j] & 0xffff0000u);
        float b_lo = __uint_as_float(A1[j] << 16), b_hi = __uint_as_float(A1[j] & 0xffff0000u);
        res[j] = cvtpk(a_lo * wa + b_lo * wb, a_hi * wa + b_hi * wb);
      }
      *(u32x4*)((char*)sA + id * 16) = res;
    }
#pragma unroll
    for (int i = 0; i < 2; i++) {
      int chunk = wid * 2 + i;
      int row = chunk * 8 + r8;
      gload16(&Bt[(c0 + row) * QD + k0 + c8l * 8], (char*)sB + chunk * 1024);
    }
    __syncthreads();
#pragma unroll
    for (int kk = 0; kk < 2; kk++) {
      bf16x8 af[4], bfr[2];
#pragma unroll
      for (int t = 0; t < 4; t++) af[t] = *(const bf16x8*)&sA[(wm * 64 + t * 16 + lo) * 64 + (kk * 4 + hi) * 8];
#pragma unroll
      for (int u = 0; u < 2; u++) bfr[u] = *(const bf16x8*)&sB[(wn * 32 + u * 16 + lo) * 64 + (kk * 4 + hi) * 8];
#pragma unroll
      for (int t = 0; t < 4; t++)
#pragma unroll
        for (int u = 0; u < 2; u++)
          acc[t][u] = __builtin_amdgcn_mfma_f32_16x16x32_bf16(af[t], bfr[u], acc[t][u], 0, 0, 0);
    }
  }
#pragma unroll
  for (int t = 0; t < 4; t++)
#pragma unroll
    for (int u = 0; u < 2; u++)
#pragma unroll
      for (int ri = 0; ri < 4; ri++) {
        int r = r0 + wm * 64 + t * 16 + hi * 4 + ri;
        int c = c0 + wn * 32 + u * 16 + lo;
        out[r * QD + c] = acc[t][u][ri] + bias[c];
      }
}

extern "C" void kernel_launch(void* const* d_in, const int* in_sizes, int n_in,
                              void* d_out, int out_size, void* d_ws, size_t ws_size,
                              hipStream_t stream) {
  const float* x   = (const float*)d_in[0];
  const float* ctx = (const float*)d_in[1];
  const float* Wq  = (const float*)d_in[2];
  const float* Wk  = (const float*)d_in[3];
  const float* Wv  = (const float*)d_in[4];
  const float* Wo  = (const float*)d_in[5];
  const float* bo  = (const float*)d_in[6];
  char* ws = (char*)d_ws;

  // po (16 MB) aliases xb+cb (dead after qkv_gemm, before flash_attn writes po)
  unsigned short* xb   = (unsigned short*)(ws);              // 8 MB
  unsigned short* cb   = (unsigned short*)(ws + 8388608);    // 8 MB
  unsigned short* po   = (unsigned short*)(ws);              // 16 MB, [half][bh][q][64]
  unsigned short* wqt  = (unsigned short*)(ws + 16777216);   // 512 KB each
  unsigned short* wkt  = (unsigned short*)(ws + 17301504);
  unsigned short* wvt  = (unsigned short*)(ws + 17825792);
  unsigned short* wot  = (unsigned short*)(ws + 18350080);
  unsigned short* q_ws = (unsigned short*)(ws + 18874368);   // 8 MB, [bh][n][64]
  unsigned short* k_ws = (unsigned short*)(ws + 27262976);   // 8 MB, [bh][m][64]
  unsigned short* v_ws = (unsigned short*)(ws + 35651584);   // 8 MB, [bh][64][m]
  float*          pml  = (float*)(ws + 44040192);            // 512 KB, [half][bh*2048+q]
  float* out = (float*)d_out;

  cvt_inputs<<<4096, 256, 0, stream>>>(x, ctx, xb, cb);
  cvt_weights<<<dim3(16, 16, 4), dim3(32, 8), 0, stream>>>(Wq, Wk, Wv, Wo, wqt, wkt, wvt, wot);

  qkv_gemm<<<dim3(4, 64, 3), 256, 0, stream>>>(xb, cb, wqt, wkt, wvt, q_ws, k_ws, v_ws);

  flash_attn<<<dim3(32, 8, 2), 512, 0, stream>>>(q_ws, k_ws, v_ws, po, pml);

  out_gemm<<<dim3(64, 8), 256, 0, stream>>>(po, pml, wot, out, bo);
}

// Round 8
// 99.454 us; speedup vs baseline: 1.1647x; 1.1277x over previous
//
#include <hip/hip_runtime.h>

// CrossAttention: x[4,2048,512], context[4,2048,512], Wq/Wk/Wv[512,512], Wo[512,512], bo[512]
// out = softmax(QK^T/sqrt(64)) V -> @Wo + bo.  All-bf16 MFMA pipeline, fp32 accum.
// R8: z=2 (V^T) epilogue via LDS-transpose bounce -> coalesced 16B stores (kills the
//     64-transactions-per-store scatter that pinned qkv at ~50us); grid rowblk-fastest.

typedef short bf16x8 __attribute__((ext_vector_type(8)));
typedef float f32x4 __attribute__((ext_vector_type(4)));
typedef float f32x16 __attribute__((ext_vector_type(16)));
typedef unsigned int u32x4 __attribute__((ext_vector_type(4)));
typedef unsigned short u16x8 __attribute__((ext_vector_type(8)));

#define NB 4
#define NN 2048
#define QD 512
#define DH 64
// log2(e)/sqrt(DH): folded into Q so softmax runs in exp2 domain
#define QSCALE 0.18033688011112042f

__device__ __forceinline__ unsigned short f2bf(float f) {
  unsigned u = __float_as_uint(f);
  unsigned r = (u + 0x7fffu + ((u >> 16) & 1u)) >> 16;
  return (unsigned short)r;
}

__device__ __forceinline__ unsigned cvtpk(float a, float b) {
  unsigned r;
  asm("v_cvt_pk_bf16_f32 %0, %1, %2" : "=v"(r) : "v"(a), "v"(b));
  return r;
}

__device__ __forceinline__ void pl32swap(unsigned& a, unsigned& b) {
  asm("v_permlane32_swap_b32 %0, %1" : "+v"(a), "+v"(b));
}

__device__ __forceinline__ void gload16(const void* g, void* l) {
  __builtin_amdgcn_global_load_lds((const __attribute__((address_space(1))) unsigned int*)g,
                                   (__attribute__((address_space(3))) unsigned int*)l, 16, 0, 0);
}

// ---------------- convert x / context to bf16 ----------------
__global__ __launch_bounds__(256) void cvt_inputs(const float* __restrict__ x,
                                                  const float* __restrict__ ctx,
                                                  unsigned short* __restrict__ xb,
                                                  unsigned short* __restrict__ cb) {
  int i = blockIdx.x * 256 + threadIdx.x;
  const int total = (NB * NN * QD) / 4;
  if (i < total) {
    float4 v = ((const float4*)x)[i];
    ushort4 o;
    o.x = f2bf(v.x); o.y = f2bf(v.y); o.z = f2bf(v.z); o.w = f2bf(v.w);
    ((ushort4*)xb)[i] = o;
    float4 w = ((const float4*)ctx)[i];
    ushort4 p;
    p.x = f2bf(w.x); p.y = f2bf(w.y); p.z = f2bf(w.z); p.w = f2bf(w.w);
    ((ushort4*)cb)[i] = p;
  }
}

// ---------------- transpose weights to [col][k] bf16 ----------------
__global__ __launch_bounds__(256) void cvt_weights(const float* __restrict__ Wq, const float* __restrict__ Wk,
                                                   const float* __restrict__ Wv, const float* __restrict__ Wo,
                                                   unsigned short* __restrict__ wqt, unsigned short* __restrict__ wkt,
                                                   unsigned short* __restrict__ wvt, unsigned short* __restrict__ wot) {
  __shared__ float t[32][33];
  const float* W = blockIdx.z == 0 ? Wq : blockIdx.z == 1 ? Wk : blockIdx.z == 2 ? Wv : Wo;
  unsigned short* O = blockIdx.z == 0 ? wqt : blockIdx.z == 1 ? wkt : blockIdx.z == 2 ? wvt : wot;
  int c0 = blockIdx.x * 32, k0 = blockIdx.y * 32;
  int tx = threadIdx.x, ty = threadIdx.y;  // 32 x 8
#pragma unroll
  for (int j = 0; j < 4; j++) t[ty + 8 * j][tx] = W[(k0 + ty + 8 * j) * QD + c0 + tx];
  __syncthreads();
#pragma unroll
  for (int j = 0; j < 4; j++) O[(c0 + ty + 8 * j) * QD + k0 + tx] = f2bf(t[tx][ty + 8 * j]);
}

// ---------------- fused QKV projection: gload dbuf + LDS-bounce V^T epilogue ----------------
// grid (64 rowblk, 4 colblk, 3 z). 128x128 tile, BK=64, 4 waves (2x2). LDS 64 KB.
__global__ __launch_bounds__(256, 2) void qkv_gemm(const unsigned short* __restrict__ xb,
                                                   const unsigned short* __restrict__ cb,
                                                   const unsigned short* __restrict__ wqt,
                                                   const unsigned short* __restrict__ wkt,
                                                   const unsigned short* __restrict__ wvt,
                                                   unsigned short* __restrict__ q_ws,
                                                   unsigned short* __restrict__ k_ws,
                                                   unsigned short* __restrict__ v_ws) {
  __shared__ __align__(16) char sAB[2][32768];  // [buf][A 128x64 | B 128x64]; reused as bounce
  const int z = blockIdx.z;
  const unsigned short* A = (z == 0) ? xb : cb;
  const unsigned short* Bt = (z == 0) ? wqt : (z == 1) ? wkt : wvt;
  const int lane = threadIdx.x & 63, wid = threadIdx.x >> 6;
  const int lo = lane & 15, hi = lane >> 4;
  const int wm = wid >> 1, wn = wid & 1;
  const int r0 = blockIdx.x * 128, c0 = blockIdx.y * 128;
  const int r8 = lane >> 3, c8l = lane & 7;

#define STAGEQ(K0, BUF)                                                      \
  do {                                                                       \
    char* b_ = sAB[BUF];                                                     \
    _Pragma("unroll") for (int i_ = 0; i_ < 4; ++i_) {                       \
      int chunk_ = wid * 4 + i_;                                             \
      int row_ = chunk_ * 8 + r8;                                            \
      gload16(&A[(r0 + row_) * QD + (K0) + c8l * 8], b_ + chunk_ * 1024);    \
      gload16(&Bt[(c0 + row_) * QD + (K0) + c8l * 8],                        \
              b_ + 16384 + chunk_ * 1024);                                   \
    }                                                                        \
  } while (0)

  f32x4 acc[4][4] = {};
  STAGEQ(0, 0);
  for (int ks = 0; ks < 8; ++ks) {
    asm volatile("s_waitcnt vmcnt(0)" ::: "memory");  // own stage(ks) writes landed
    __builtin_amdgcn_s_barrier();                      // all stage(ks) done; buf(ks^1) consumed
    __builtin_amdgcn_sched_barrier(0);
    if (ks + 1 < 8) STAGEQ((ks + 1) * 64, (ks + 1) & 1);
    const unsigned short* sA = (const unsigned short*)sAB[ks & 1];
    const unsigned short* sB = sA + 8192;
#pragma unroll
    for (int kk = 0; kk < 2; kk++) {
      bf16x8 af[4], bfr[4];
#pragma unroll
      for (int t = 0; t < 4; t++) af[t] = *(const bf16x8*)&sA[(wm * 64 + t * 16 + lo) * 64 + (kk * 4 + hi) * 8];
#pragma unroll
      for (int u = 0; u < 4; u++) bfr[u] = *(const bf16x8*)&sB[(wn * 64 + u * 16 + lo) * 64 + (kk * 4 + hi) * 8];
#pragma unroll
      for (int t = 0; t < 4; t++)
#pragma unroll
        for (int u = 0; u < 4; u++)
          acc[t][u] = __builtin_amdgcn_mfma_f32_16x16x32_bf16(af[t], bfr[u], acc[t][u], 0, 0, 0);
    }
  }
#undef STAGEQ

  if (z == 2) {
    // V^T epilogue: bounce through LDS [128 hd][136 m] (pad 8 -> 2-way conflicts max),
    // then coalesced 16B stores: row hd -> V^T[(b*8+h)*64+d][r0 + m].
    __syncthreads();  // k-loop LDS reads done before overwrite
    unsigned short* tb = (unsigned short*)sAB;
#pragma unroll
    for (int t = 0; t < 4; t++)
#pragma unroll
      for (int u = 0; u < 4; u++)
#pragma unroll
        for (int ri = 0; ri < 4; ri++) {
          int rloc = wm * 64 + t * 16 + hi * 4 + ri;   // m within tile
          int cloc = wn * 64 + u * 16 + lo;            // hd within tile
          tb[cloc * 136 + rloc] = f2bf(acc[t][u][ri]);
        }
    __syncthreads();
    const int b = r0 >> 11, n0 = r0 & 2047;
#pragma unroll
    for (int i = 0; i < 8; i++) {
      int hd = i * 16 + (threadIdx.x >> 4);
      int mcol = (threadIdx.x & 15) * 8;
      u16x8 v = *(const u16x8*)&tb[hd * 136 + mcol];
      int h = (c0 + hd) >> 6, d = (c0 + hd) & 63;
      *(u16x8*)&v_ws[(((b << 3) | h) * DH + d) * NN + n0 + mcol] = v;
    }
  } else {
    const float outscale = (z == 0) ? QSCALE : 1.0f;
    unsigned short* Cq = (z == 0) ? q_ws : k_ws;
#pragma unroll
    for (int t = 0; t < 4; t++)
#pragma unroll
      for (int u = 0; u < 4; u++)
#pragma unroll
        for (int ri = 0; ri < 4; ri++) {
          int r = r0 + wm * 64 + t * 16 + hi * 4 + ri;
          int c = c0 + wn * 64 + u * 16 + lo;
          float v = acc[t][u][ri] * outscale;
          int b = r >> 11, n = r & 2047, h = c >> 6, d = c & 63;
          Cq[(((b << 3) | h) * NN + n) * DH + d] = f2bf(v);
        }
  }
}

// ---------------- flash attention: 8-wave, KVBLK=64, fixed-max, split-KV (R5, proven) ----------------
__global__ __launch_bounds__(512, 4) void flash_attn(const unsigned short* __restrict__ Q,
                                                     const unsigned short* __restrict__ K,
                                                     const unsigned short* __restrict__ Vt,
                                                     unsigned short* __restrict__ po,
                                                     float* __restrict__ pml) {
  __shared__ __align__(16) char sKV[2][16384];  // [buf][K 64x64 | V^T 64x64]
  const int tid = threadIdx.x;
  const int lane = tid & 63, wid = tid >> 6;
  const int l31 = lane & 31, hi = lane >> 5;
  const int bh = blockIdx.x, half = blockIdx.z;
  const int bhK = bh * NN, bhV = bh * DH;
  const int kv0 = half * (NN / 2);
  const int qrow = blockIdx.y * 256 + wid * 32 + l31;
  po += half * (32 * 2048 * 64);
  pml += half * (32 * 2048);

  // Q fragments (B-operand): col=q(=l31), k(d) = ks*16 + hi*8 + j
  bf16x8 qf[4];
#pragma unroll
  for (int ks = 0; ks < 4; ks++)
    qf[ks] = *(const bf16x8*)&Q[(bhK + qrow) * DH + ks * 16 + hi * 8];

  // staging role: thread t handles chunk t of K region and chunk t of V region
  const int row_s = tid >> 3, slot_s = tid & 7;
  const int swz = (slot_s ^ (row_s & 7)) * 8;

#define STAGE(J0, BUF)                                                     \
  do {                                                                     \
    char* b_ = (char*)sKV[BUF];                                            \
    gload16(&K[(bhK + (J0) + row_s) * DH + swz], b_ + wid * 1024);         \
    gload16(&Vt[(bhV + row_s) * NN + (J0) + swz], b_ + 8192 + wid * 1024); \
  } while (0)

  float l = 0.f;
  f32x16 o[2] = {};

  STAGE(kv0, 0);

  for (int it = 0; it < 16; ++it) {
    asm volatile("s_waitcnt vmcnt(0)" ::: "memory");  // own stage(it) writes done
    __builtin_amdgcn_s_barrier();                      // all stage(it) done; buf(it+1) consumed
    __builtin_amdgcn_sched_barrier(0);
    if (it + 1 < 16) STAGE(kv0 + (it + 1) * 64, (it + 1) & 1);
    const char* buf = (const char*)sKV[it & 1];

    // S^T[key][q] = K . Q^T  (2 key-tiles of 32, 4 d-slices of 16)
    f32x16 st[2] = {};
    __builtin_amdgcn_s_setprio(1);
#pragma unroll
    for (int g = 0; g < 2; g++)
#pragma unroll
      for (int ks = 0; ks < 4; ks++) {
        bf16x8 kf = *(const bf16x8*)(buf + (g * 32 + l31) * 128 + (((ks * 2 + hi) ^ (l31 & 7)) << 4));
        st[g] = __builtin_amdgcn_mfma_f32_32x32x16_bf16(kf, qf[ks], st[g], 0, 0, 0);
      }
    __builtin_amdgcn_s_setprio(0);

    // fixed-max softmax (m = 0; shift-invariant, logits hard-bounded far below fp32 overflow)
#pragma unroll
    for (int g = 0; g < 2; g++)
#pragma unroll
      for (int c = 0; c < 16; c++) st[g][c] = __builtin_amdgcn_exp2f(st[g][c]);
    float s8[8];
#pragma unroll
    for (int c = 0; c < 8; c++) s8[c] = (st[0][c] + st[0][c + 8]) + (st[1][c] + st[1][c + 8]);
#pragma unroll
    for (int w = 4; w >= 1; w >>= 1)
#pragma unroll
      for (int c = 0; c < 4; c++)
        if (c < w) s8[c] += s8[c + w];
    l += s8[0] + __shfl_xor(s8[0], 32);

    // P -> bf16 B-fragments (verified mapping):
    // (w0,w2)=swap(pk(c0,c1),pk(c4,c5)); (w1,w3)=swap(pk(c2,c3),pk(c6,c7)); cb=s*8.
    bf16x8 pf[2][2];
#pragma unroll
    for (int g = 0; g < 2; g++)
#pragma unroll
      for (int s = 0; s < 2; s++) {
        const int cb = s * 8;
        unsigned a0 = cvtpk(st[g][cb + 0], st[g][cb + 1]);
        unsigned a1 = cvtpk(st[g][cb + 2], st[g][cb + 3]);
        unsigned b0 = cvtpk(st[g][cb + 4], st[g][cb + 5]);
        unsigned b1 = cvtpk(st[g][cb + 6], st[g][cb + 7]);
        pl32swap(a0, b0);
        pl32swap(a1, b1);
        union { unsigned u[4]; bf16x8 v; } pu;
        pu.u[0] = a0; pu.u[1] = a1; pu.u[2] = b0; pu.u[3] = b1;
        pf[g][s] = pu.v;
      }

    // O^T[d][q] += V^T . P^T  (2 d-tiles x 2 key-tiles x 2 slices)
    __builtin_amdgcn_s_setprio(1);
#pragma unroll
    for (int dt = 0; dt < 2; dt++)
#pragma unroll
      for (int g = 0; g < 2; g++)
#pragma unroll
        for (int s = 0; s < 2; s++) {
          int row = dt * 32 + l31;
          bf16x8 vf = *(const bf16x8*)(buf + 8192 + row * 128 + (((g * 4 + s * 2 + hi) ^ (row & 7)) << 4));
          o[dt] = __builtin_amdgcn_mfma_f32_32x32x16_bf16(vf, pf[g][s], o[dt], 0, 0, 0);
        }
    __builtin_amdgcn_s_setprio(0);
  }
#undef STAGE

  // store partial: o normalized by own l (bf16); l (f32)
  float inv = 1.f / l;
  const int rbase = (bh * 2048 + qrow) * 64;
#pragma unroll
  for (int dt = 0; dt < 2; dt++)
#pragma unroll
    for (int cg = 0; cg < 4; cg++) {
      ushort4 w;
      w.x = f2bf(o[dt][cg * 4 + 0] * inv);
      w.y = f2bf(o[dt][cg * 4 + 1] * inv);
      w.z = f2bf(o[dt][cg * 4 + 2] * inv);
      w.w = f2bf(o[dt][cg * 4 + 3] * inv);
      int d0 = dt * 32 + cg * 8 + hi * 4;
      *(ushort4*)&po[rbase + d0] = w;
    }
  if (hi == 0) pml[bh * 2048 + qrow] = l;
}

// ---------------- output projection with fused split-KV combine (R5, proven) ----------------
__global__ __launch_bounds__(256, 2) void out_gemm(const unsigned short* __restrict__ po,
                                                   const float* __restrict__ pml,
                                                   const unsigned short* __restrict__ Bt,
                                                   float* __restrict__ out,
                                                   const float* __restrict__ bias) {
  __shared__ __align__(16) unsigned short sA[128 * 64];
  __shared__ __align__(16) unsigned short sB[64 * 64];
  const unsigned short* po1 = po + 32 * 2048 * 64;
  const float* pml1 = pml + 32 * 2048;
  const int lane = threadIdx.x & 63, wid = threadIdx.x >> 6;
  const int lo = lane & 15, hi = lane >> 4;
  const int wm = wid >> 1, wn = wid & 1;
  const int r0 = blockIdx.x * 128, c0 = blockIdx.y * 64;
  const int r8 = lane >> 3, c8l = lane & 7;
  f32x4 acc[4][2] = {};
  for (int k0 = 0; k0 < QD; k0 += 64) {
    __syncthreads();
    const int h = k0 >> 6;
#pragma unroll
    for (int i = 0; i < 4; i++) {
      int id = i * 256 + threadIdx.x;
      int row = id >> 3, slot = id & 7;
      int r = r0 + row, b = r >> 11, n = r & 2047;
      int pr = ((b << 3) | h) * NN + n;
      float la = pml[pr], lb = pml1[pr];
      float s = __builtin_amdgcn_rcpf(la + lb);
      float wa = la * s, wb = lb * s;
      u32x4 A0 = *(const u32x4*)&po[pr * 64 + slot * 8];
      u32x4 A1 = *(const u32x4*)&po1[pr * 64 + slot * 8];
      u32x4 res;
#pragma unroll
      for (int j = 0; j < 4; j++) {
        float a_lo = __uint_as_float(A0[j] << 16), a_hi = __uint_as_float(A0[j] & 0xffff0000u);
        float b_lo = __uint_as_float(A1[j] << 16), b_hi = __uint_as_float(A1[j] & 0xffff0000u);
        res[j] = cvtpk(a_lo * wa + b_lo * wb, a_hi * wa + b_hi * wb);
      }
      *(u32x4*)((char*)sA + id * 16) = res;
    }
#pragma unroll
    for (int i = 0; i < 2; i++) {
      int chunk = wid * 2 + i;
      int row = chunk * 8 + r8;
      gload16(&Bt[(c0 + row) * QD + k0 + c8l * 8], (char*)sB + chunk * 1024);
    }
    __syncthreads();
#pragma unroll
    for (int kk = 0; kk < 2; kk++) {
      bf16x8 af[4], bfr[2];
#pragma unroll
      for (int t = 0; t < 4; t++) af[t] = *(const bf16x8*)&sA[(wm * 64 + t * 16 + lo) * 64 + (kk * 4 + hi) * 8];
#pragma unroll
      for (int u = 0; u < 2; u++) bfr[u] = *(const bf16x8*)&sB[(wn * 32 + u * 16 + lo) * 64 + (kk * 4 + hi) * 8];
#pragma unroll
      for (int t = 0; t < 4; t++)
#pragma unroll
        for (int u = 0; u < 2; u++)
          acc[t][u] = __builtin_amdgcn_mfma_f32_16x16x32_bf16(af[t], bfr[u], acc[t][u], 0, 0, 0);
    }
  }
#pragma unroll
  for (int t = 0; t < 4; t++)
#pragma unroll
    for (int u = 0; u < 2; u++)
#pragma unroll
      for (int ri = 0; ri < 4; ri++) {
        int r = r0 + wm * 64 + t * 16 + hi * 4 + ri;
        int c = c0 + wn * 32 + u * 16 + lo;
        out[r * QD + c] = acc[t][u][ri] + bias[c];
      }
}

extern "C" void kernel_launch(void* const* d_in, const int* in_sizes, int n_in,
                              void* d_out, int out_size, void* d_ws, size_t ws_size,
                              hipStream_t stream) {
  const float* x   = (const float*)d_in[0];
  const float* ctx = (const float*)d_in[1];
  const float* Wq  = (const float*)d_in[2];
  const float* Wk  = (const float*)d_in[3];
  const float* Wv  = (const float*)d_in[4];
  const float* Wo  = (const float*)d_in[5];
  const float* bo  = (const float*)d_in[6];
  char* ws = (char*)d_ws;

  // po (16 MB) aliases xb+cb (dead after qkv_gemm, before flash_attn writes po)
  unsigned short* xb   = (unsigned short*)(ws);              // 8 MB
  unsigned short* cb   = (unsigned short*)(ws + 8388608);    // 8 MB
  unsigned short* po   = (unsigned short*)(ws);              // 16 MB, [half][bh][q][64]
  unsigned short* wqt  = (unsigned short*)(ws + 16777216);   // 512 KB each
  unsigned short* wkt  = (unsigned short*)(ws + 17301504);
  unsigned short* wvt  = (unsigned short*)(ws + 17825792);
  unsigned short* wot  = (unsigned short*)(ws + 18350080);
  unsigned short* q_ws = (unsigned short*)(ws + 18874368);   // 8 MB, [bh][n][64]
  unsigned short* k_ws = (unsigned short*)(ws + 27262976);   // 8 MB, [bh][m][64]
  unsigned short* v_ws = (unsigned short*)(ws + 35651584);   // 8 MB, [bh][64][m]
  float*          pml  = (float*)(ws + 44040192);            // 512 KB, [half][bh*2048+q]
  float* out = (float*)d_out;

  cvt_inputs<<<4096, 256, 0, stream>>>(x, ctx, xb, cb);
  cvt_weights<<<dim3(16, 16, 4), dim3(32, 8), 0, stream>>>(Wq, Wk, Wv, Wo, wqt, wkt, wvt, wot);

  qkv_gemm<<<dim3(64, 4, 3), 256, 0, stream>>>(xb, cb, wqt, wkt, wvt, q_ws, k_ws, v_ws);

  flash_attn<<<dim3(32, 8, 2), 512, 0, stream>>>(q_ws, k_ws, v_ws, po, pml);

  out_gemm<<<dim3(64, 8), 256, 0, stream>>>(po, pml, wot, out, bo);
}

// Round 9
// 99.424 us; speedup vs baseline: 1.1650x; 1.0003x over previous
//
#include <hip/hip_runtime.h>

// CrossAttention: x[4,2048,512], context[4,2048,512], Wq/Wk/Wv[512,512], Wo[512,512], bo[512]
// out = softmax(QK^T/sqrt(64)) V -> @Wo + bo.  All-bf16 MFMA pipeline, fp32 accum.
// R9: flash_attn 64 q-rows/wave (2 Q-tiles) -> each K/V LDS fragment feeds 2 MFMAs,
//     halving LDS-read traffic per FLOP (R8 diagnosis: LDS-BW-bound at 1:1 read:MFMA).

typedef short bf16x8 __attribute__((ext_vector_type(8)));
typedef float f32x4 __attribute__((ext_vector_type(4)));
typedef float f32x16 __attribute__((ext_vector_type(16)));
typedef unsigned int u32x4 __attribute__((ext_vector_type(4)));
typedef unsigned short u16x8 __attribute__((ext_vector_type(8)));

#define NB 4
#define NN 2048
#define QD 512
#define DH 64
// log2(e)/sqrt(DH): folded into Q so softmax runs in exp2 domain
#define QSCALE 0.18033688011112042f

__device__ __forceinline__ unsigned short f2bf(float f) {
  unsigned u = __float_as_uint(f);
  unsigned r = (u + 0x7fffu + ((u >> 16) & 1u)) >> 16;
  return (unsigned short)r;
}

__device__ __forceinline__ unsigned cvtpk(float a, float b) {
  unsigned r;
  asm("v_cvt_pk_bf16_f32 %0, %1, %2" : "=v"(r) : "v"(a), "v"(b));
  return r;
}

__device__ __forceinline__ void pl32swap(unsigned& a, unsigned& b) {
  asm("v_permlane32_swap_b32 %0, %1" : "+v"(a), "+v"(b));
}

__device__ __forceinline__ void gload16(const void* g, void* l) {
  __builtin_amdgcn_global_load_lds((const __attribute__((address_space(1))) unsigned int*)g,
                                   (__attribute__((address_space(3))) unsigned int*)l, 16, 0, 0);
}

// ---------------- convert x / context to bf16 ----------------
__global__ __launch_bounds__(256) void cvt_inputs(const float* __restrict__ x,
                                                  const float* __restrict__ ctx,
                                                  unsigned short* __restrict__ xb,
                                                  unsigned short* __restrict__ cb) {
  int i = blockIdx.x * 256 + threadIdx.x;
  const int total = (NB * NN * QD) / 4;
  if (i < total) {
    float4 v = ((const float4*)x)[i];
    ushort4 o;
    o.x = f2bf(v.x); o.y = f2bf(v.y); o.z = f2bf(v.z); o.w = f2bf(v.w);
    ((ushort4*)xb)[i] = o;
    float4 w = ((const float4*)ctx)[i];
    ushort4 p;
    p.x = f2bf(w.x); p.y = f2bf(w.y); p.z = f2bf(w.z); p.w = f2bf(w.w);
    ((ushort4*)cb)[i] = p;
  }
}

// ---------------- transpose weights to [col][k] bf16 ----------------
__global__ __launch_bounds__(256) void cvt_weights(const float* __restrict__ Wq, const float* __restrict__ Wk,
                                                   const float* __restrict__ Wv, const float* __restrict__ Wo,
                                                   unsigned short* __restrict__ wqt, unsigned short* __restrict__ wkt,
                                                   unsigned short* __restrict__ wvt, unsigned short* __restrict__ wot) {
  __shared__ float t[32][33];
  const float* W = blockIdx.z == 0 ? Wq : blockIdx.z == 1 ? Wk : blockIdx.z == 2 ? Wv : Wo;
  unsigned short* O = blockIdx.z == 0 ? wqt : blockIdx.z == 1 ? wkt : blockIdx.z == 2 ? wvt : wot;
  int c0 = blockIdx.x * 32, k0 = blockIdx.y * 32;
  int tx = threadIdx.x, ty = threadIdx.y;  // 32 x 8
#pragma unroll
  for (int j = 0; j < 4; j++) t[ty + 8 * j][tx] = W[(k0 + ty + 8 * j) * QD + c0 + tx];
  __syncthreads();
#pragma unroll
  for (int j = 0; j < 4; j++) O[(c0 + ty + 8 * j) * QD + k0 + tx] = f2bf(t[tx][ty + 8 * j]);
}

// ---------------- fused QKV projection: gload dbuf + LDS-bounce V^T epilogue (R8, proven) ----------------
__global__ __launch_bounds__(256, 2) void qkv_gemm(const unsigned short* __restrict__ xb,
                                                   const unsigned short* __restrict__ cb,
                                                   const unsigned short* __restrict__ wqt,
                                                   const unsigned short* __restrict__ wkt,
                                                   const unsigned short* __restrict__ wvt,
                                                   unsigned short* __restrict__ q_ws,
                                                   unsigned short* __restrict__ k_ws,
                                                   unsigned short* __restrict__ v_ws) {
  __shared__ __align__(16) char sAB[2][32768];  // [buf][A 128x64 | B 128x64]; reused as bounce
  const int z = blockIdx.z;
  const unsigned short* A = (z == 0) ? xb : cb;
  const unsigned short* Bt = (z == 0) ? wqt : (z == 1) ? wkt : wvt;
  const int lane = threadIdx.x & 63, wid = threadIdx.x >> 6;
  const int lo = lane & 15, hi = lane >> 4;
  const int wm = wid >> 1, wn = wid & 1;
  const int r0 = blockIdx.x * 128, c0 = blockIdx.y * 128;
  const int r8 = lane >> 3, c8l = lane & 7;

#define STAGEQ(K0, BUF)                                                      \
  do {                                                                       \
    char* b_ = sAB[BUF];                                                     \
    _Pragma("unroll") for (int i_ = 0; i_ < 4; ++i_) {                       \
      int chunk_ = wid * 4 + i_;                                             \
      int row_ = chunk_ * 8 + r8;                                            \
      gload16(&A[(r0 + row_) * QD + (K0) + c8l * 8], b_ + chunk_ * 1024);    \
      gload16(&Bt[(c0 + row_) * QD + (K0) + c8l * 8],                        \
              b_ + 16384 + chunk_ * 1024);                                   \
    }                                                                        \
  } while (0)

  f32x4 acc[4][4] = {};
  STAGEQ(0, 0);
  for (int ks = 0; ks < 8; ++ks) {
    asm volatile("s_waitcnt vmcnt(0)" ::: "memory");  // own stage(ks) writes landed
    __builtin_amdgcn_s_barrier();                      // all stage(ks) done; buf(ks^1) consumed
    __builtin_amdgcn_sched_barrier(0);
    if (ks + 1 < 8) STAGEQ((ks + 1) * 64, (ks + 1) & 1);
    const unsigned short* sA = (const unsigned short*)sAB[ks & 1];
    const unsigned short* sB = sA + 8192;
#pragma unroll
    for (int kk = 0; kk < 2; kk++) {
      bf16x8 af[4], bfr[4];
#pragma unroll
      for (int t = 0; t < 4; t++) af[t] = *(const bf16x8*)&sA[(wm * 64 + t * 16 + lo) * 64 + (kk * 4 + hi) * 8];
#pragma unroll
      for (int u = 0; u < 4; u++) bfr[u] = *(const bf16x8*)&sB[(wn * 64 + u * 16 + lo) * 64 + (kk * 4 + hi) * 8];
#pragma unroll
      for (int t = 0; t < 4; t++)
#pragma unroll
        for (int u = 0; u < 4; u++)
          acc[t][u] = __builtin_amdgcn_mfma_f32_16x16x32_bf16(af[t], bfr[u], acc[t][u], 0, 0, 0);
    }
  }
#undef STAGEQ

  if (z == 2) {
    // V^T epilogue: bounce through LDS [128 hd][136 m] (pad 8 -> 2-way conflicts max),
    // then coalesced 16B stores: row hd -> V^T[(b*8+h)*64+d][r0 + m].
    __syncthreads();  // k-loop LDS reads done before overwrite
    unsigned short* tb = (unsigned short*)sAB;
#pragma unroll
    for (int t = 0; t < 4; t++)
#pragma unroll
      for (int u = 0; u < 4; u++)
#pragma unroll
        for (int ri = 0; ri < 4; ri++) {
          int rloc = wm * 64 + t * 16 + hi * 4 + ri;   // m within tile
          int cloc = wn * 64 + u * 16 + lo;            // hd within tile
          tb[cloc * 136 + rloc] = f2bf(acc[t][u][ri]);
        }
    __syncthreads();
    const int b = r0 >> 11, n0 = r0 & 2047;
#pragma unroll
    for (int i = 0; i < 8; i++) {
      int hd = i * 16 + (threadIdx.x >> 4);
      int mcol = (threadIdx.x & 15) * 8;
      u16x8 v = *(const u16x8*)&tb[hd * 136 + mcol];
      int h = (c0 + hd) >> 6, d = (c0 + hd) & 63;
      *(u16x8*)&v_ws[(((b << 3) | h) * DH + d) * NN + n0 + mcol] = v;
    }
  } else {
    const float outscale = (z == 0) ? QSCALE : 1.0f;
    unsigned short* Cq = (z == 0) ? q_ws : k_ws;
#pragma unroll
    for (int t = 0; t < 4; t++)
#pragma unroll
      for (int u = 0; u < 4; u++)
#pragma unroll
        for (int ri = 0; ri < 4; ri++) {
          int r = r0 + wm * 64 + t * 16 + hi * 4 + ri;
          int c = c0 + wn * 64 + u * 16 + lo;
          float v = acc[t][u][ri] * outscale;
          int b = r >> 11, n = r & 2047, h = c >> 6, d = c & 63;
          Cq[(((b << 3) | h) * NN + n) * DH + d] = f2bf(v);
        }
  }
}

// ---------------- flash attention: 4 waves x 64 q-rows, KVBLK=64, fixed-max, split-KV ----------------
// grid (32 bh, 8 qblk, 2 kv-half), 256 thr = 4 waves. Wave owns 64 q rows = 2 Q-tiles of 32
// (q = l31 within tile). Each K/V LDS fragment feeds 2 MFMAs (one per Q-tile) -> LDS traffic
// per FLOP halved vs R8. LDS image identical to R8 (staging re-chunked for 4 waves).
__global__ __launch_bounds__(256, 2) void flash_attn(const unsigned short* __restrict__ Q,
                                                     const unsigned short* __restrict__ K,
                                                     const unsigned short* __restrict__ Vt,
                                                     unsigned short* __restrict__ po,
                                                     float* __restrict__ pml) {
  __shared__ __align__(16) char sKV[2][16384];  // [buf][K 64x64 | V^T 64x64]
  const int tid = threadIdx.x;
  const int lane = tid & 63, wid = tid >> 6;
  const int l31 = lane & 31, hi = lane >> 5;
  const int bh = blockIdx.x, half = blockIdx.z;
  const int bhK = bh * NN, bhV = bh * DH;
  const int kv0 = half * (NN / 2);
  const int qbase = blockIdx.y * 256 + wid * 64;
  po += half * (32 * 2048 * 64);
  pml += half * (32 * 2048);

  // Q fragments (B-operand) for the 2 Q-tiles: col=q(=l31), k(d) = ks*16 + hi*8 + j
  bf16x8 qf[4][2];
#pragma unroll
  for (int ks = 0; ks < 4; ks++) {
    qf[ks][0] = *(const bf16x8*)&Q[(bhK + qbase + l31) * DH + ks * 16 + hi * 8];
    qf[ks][1] = *(const bf16x8*)&Q[(bhK + qbase + 32 + l31) * DH + ks * 16 + hi * 8];
  }

  // staging: 4 waves x 2 chunks each cover the 8 KB K region (and 8 KB V region)
  const int sl_s = lane & 7;

#define STAGE(J0, BUF)                                                       \
  do {                                                                       \
    char* b_ = (char*)sKV[BUF];                                              \
    _Pragma("unroll") for (int i_ = 0; i_ < 2; ++i_) {                       \
      int c_ = wid * 2 + i_;                                                 \
      int row_ = c_ * 8 + (lane >> 3);                                       \
      int sw_ = (sl_s ^ (row_ & 7)) * 8;                                     \
      gload16(&K[(bhK + (J0) + row_) * DH + sw_], b_ + c_ * 1024);           \
      gload16(&Vt[(bhV + row_) * NN + (J0) + sw_], b_ + 8192 + c_ * 1024);   \
    }                                                                        \
  } while (0)

  float l0 = 0.f, l1 = 0.f;
  f32x16 o[2][2] = {};  // [dt][qt]

  STAGE(kv0, 0);

  for (int it = 0; it < 16; ++it) {
    asm volatile("s_waitcnt vmcnt(0)" ::: "memory");  // own stage(it) writes done
    __builtin_amdgcn_s_barrier();                      // all stage(it) done; buf(it+1) consumed
    __builtin_amdgcn_sched_barrier(0);
    if (it + 1 < 16) STAGE(kv0 + (it + 1) * 64, (it + 1) & 1);
    const char* buf = (const char*)sKV[it & 1];

    // S^T[key][q] = K . Q^T  (2 key-tiles of 32, 4 d-slices of 16, 2 Q-tiles share kf)
    f32x16 st[2][2] = {};  // [g][qt]
    __builtin_amdgcn_s_setprio(1);
#pragma unroll
    for (int g = 0; g < 2; g++)
#pragma unroll
      for (int ks = 0; ks < 4; ks++) {
        bf16x8 kf = *(const bf16x8*)(buf + (g * 32 + l31) * 128 + (((ks * 2 + hi) ^ (l31 & 7)) << 4));
        st[g][0] = __builtin_amdgcn_mfma_f32_32x32x16_bf16(kf, qf[ks][0], st[g][0], 0, 0, 0);
        st[g][1] = __builtin_amdgcn_mfma_f32_32x32x16_bf16(kf, qf[ks][1], st[g][1], 0, 0, 0);
      }
    __builtin_amdgcn_s_setprio(0);

    // fixed-max softmax (m = 0; shift-invariant, logits hard-bounded far below fp32 overflow)
#pragma unroll
    for (int qt = 0; qt < 2; qt++)
#pragma unroll
      for (int g = 0; g < 2; g++)
#pragma unroll
        for (int c = 0; c < 16; c++) st[g][qt][c] = __builtin_amdgcn_exp2f(st[g][qt][c]);
    {
      float s8a[8], s8b[8];
#pragma unroll
      for (int c = 0; c < 8; c++) {
        s8a[c] = (st[0][0][c] + st[0][0][c + 8]) + (st[1][0][c] + st[1][0][c + 8]);
        s8b[c] = (st[0][1][c] + st[0][1][c + 8]) + (st[1][1][c] + st[1][1][c + 8]);
      }
#pragma unroll
      for (int w = 4; w >= 1; w >>= 1)
#pragma unroll
        for (int c = 0; c < 4; c++)
          if (c < w) { s8a[c] += s8a[c + w]; s8b[c] += s8b[c + w]; }
      l0 += s8a[0] + __shfl_xor(s8a[0], 32);
      l1 += s8b[0] + __shfl_xor(s8b[0], 32);
    }

    // P -> bf16 B-fragments (verified mapping), per Q-tile:
    // (w0,w2)=swap(pk(c0,c1),pk(c4,c5)); (w1,w3)=swap(pk(c2,c3),pk(c6,c7)); cb=s*8.
    bf16x8 pf[2][2][2];  // [g][s][qt]
#pragma unroll
    for (int g = 0; g < 2; g++)
#pragma unroll
      for (int s = 0; s < 2; s++)
#pragma unroll
        for (int qt = 0; qt < 2; qt++) {
          const int cb = s * 8;
          unsigned a0 = cvtpk(st[g][qt][cb + 0], st[g][qt][cb + 1]);
          unsigned a1 = cvtpk(st[g][qt][cb + 2], st[g][qt][cb + 3]);
          unsigned b0 = cvtpk(st[g][qt][cb + 4], st[g][qt][cb + 5]);
          unsigned b1 = cvtpk(st[g][qt][cb + 6], st[g][qt][cb + 7]);
          pl32swap(a0, b0);
          pl32swap(a1, b1);
          union { unsigned u[4]; bf16x8 v; } pu;
          pu.u[0] = a0; pu.u[1] = a1; pu.u[2] = b0; pu.u[3] = b1;
          pf[g][s][qt] = pu.v;
        }

    // O^T[d][q] += V^T . P^T  (2 d-tiles x 2 key-tiles x 2 slices, 2 Q-tiles share vf)
    __builtin_amdgcn_s_setprio(1);
#pragma unroll
    for (int dt = 0; dt < 2; dt++)
#pragma unroll
      for (int g = 0; g < 2; g++)
#pragma unroll
        for (int s = 0; s < 2; s++) {
          int row = dt * 32 + l31;
          bf16x8 vf = *(const bf16x8*)(buf + 8192 + row * 128 + (((g * 4 + s * 2 + hi) ^ (row & 7)) << 4));
          o[dt][0] = __builtin_amdgcn_mfma_f32_32x32x16_bf16(vf, pf[g][s][0], o[dt][0], 0, 0, 0);
          o[dt][1] = __builtin_amdgcn_mfma_f32_32x32x16_bf16(vf, pf[g][s][1], o[dt][1], 0, 0, 0);
        }
    __builtin_amdgcn_s_setprio(0);
  }
#undef STAGE

  // store partials per Q-tile: o normalized by own l (bf16); l (f32)
#pragma unroll
  for (int qt = 0; qt < 2; qt++) {
    float l = (qt == 0) ? l0 : l1;
    float inv = 1.f / l;
    const int qrow = qbase + qt * 32 + l31;
    const int rbase = (bh * 2048 + qrow) * 64;
#pragma unroll
    for (int dt = 0; dt < 2; dt++)
#pragma unroll
      for (int cg = 0; cg < 4; cg++) {
        ushort4 w;
        w.x = f2bf(o[dt][qt][cg * 4 + 0] * inv);
        w.y = f2bf(o[dt][qt][cg * 4 + 1] * inv);
        w.z = f2bf(o[dt][qt][cg * 4 + 2] * inv);
        w.w = f2bf(o[dt][qt][cg * 4 + 3] * inv);
        int d0 = dt * 32 + cg * 8 + hi * 4;
        *(ushort4*)&po[rbase + d0] = w;
      }
    if (hi == 0) pml[bh * 2048 + qrow] = l;
  }
}

// ---------------- output projection with fused split-KV combine (R5, proven) ----------------
__global__ __launch_bounds__(256, 2) void out_gemm(const unsigned short* __restrict__ po,
                                                   const float* __restrict__ pml,
                                                   const unsigned short* __restrict__ Bt,
                                                   float* __restrict__ out,
                                                   const float* __restrict__ bias) {
  __shared__ __align__(16) unsigned short sA[128 * 64];
  __shared__ __align__(16) unsigned short sB[64 * 64];
  const unsigned short* po1 = po + 32 * 2048 * 64;
  const float* pml1 = pml + 32 * 2048;
  const int lane = threadIdx.x & 63, wid = threadIdx.x >> 6;
  const int lo = lane & 15, hi = lane >> 4;
  const int wm = wid >> 1, wn = wid & 1;
  const int r0 = blockIdx.x * 128, c0 = blockIdx.y * 64;
  const int r8 = lane >> 3, c8l = lane & 7;
  f32x4 acc[4][2] = {};
  for (int k0 = 0; k0 < QD; k0 += 64) {
    __syncthreads();
    const int h = k0 >> 6;
#pragma unroll
    for (int i = 0; i < 4; i++) {
      int id = i * 256 + threadIdx.x;
      int row = id >> 3, slot = id & 7;
      int r = r0 + row, b = r >> 11, n = r & 2047;
      int pr = ((b << 3) | h) * NN + n;
      float la = pml[pr], lb = pml1[pr];
      float s = __builtin_amdgcn_rcpf(la + lb);
      float wa = la * s, wb = lb * s;
      u32x4 A0 = *(const u32x4*)&po[pr * 64 + slot * 8];
      u32x4 A1 = *(const u32x4*)&po1[pr * 64 + slot * 8];
      u32x4 res;
#pragma unroll
      for (int j = 0; j < 4; j++) {
        float a_lo = __uint_as_float(A0[j] << 16), a_hi = __uint_as_float(A0[j] & 0xffff0000u);
        float b_lo = __uint_as_float(A1[j] << 16), b_hi = __uint_as_float(A1[j] & 0xffff0000u);
        res[j] = cvtpk(a_lo * wa + b_lo * wb, a_hi * wa + b_hi * wb);
      }
      *(u32x4*)((char*)sA + id * 16) = res;
    }
#pragma unroll
    for (int i = 0; i < 2; i++) {
      int chunk = wid * 2 + i;
      int row = chunk * 8 + r8;
      gload16(&Bt[(c0 + row) * QD + k0 + c8l * 8], (char*)sB + chunk * 1024);
    }
    __syncthreads();
#pragma unroll
    for (int kk = 0; kk < 2; kk++) {
      bf16x8 af[4], bfr[2];
#pragma unroll
      for (int t = 0; t < 4; t++) af[t] = *(const bf16x8*)&sA[(wm * 64 + t * 16 + lo) * 64 + (kk * 4 + hi) * 8];
#pragma unroll
      for (int u = 0; u < 2; u++) bfr[u] = *(const bf16x8*)&sB[(wn * 32 + u * 16 + lo) * 64 + (kk * 4 + hi) * 8];
#pragma unroll
      for (int t = 0; t < 4; t++)
#pragma unroll
        for (int u = 0; u < 2; u++)
          acc[t][u] = __builtin_amdgcn_mfma_f32_16x16x32_bf16(af[t], bfr[u], acc[t][u], 0, 0, 0);
    }
  }
#pragma unroll
  for (int t = 0; t < 4; t++)
#pragma unroll
    for (int u = 0; u < 2; u++)
#pragma unroll
      for (int ri = 0; ri < 4; ri++) {
        int r = r0 + wm * 64 + t * 16 + hi * 4 + ri;
        int c = c0 + wn * 32 + u * 16 + lo;
        out[r * QD + c] = acc[t][u][ri] + bias[c];
      }
}

extern "C" void kernel_launch(void* const* d_in, const int* in_sizes, int n_in,
                              void* d_out, int out_size, void* d_ws, size_t ws_size,
                              hipStream_t stream) {
  const float* x   = (const float*)d_in[0];
  const float* ctx = (const float*)d_in[1];
  const float* Wq  = (const float*)d_in[2];
  const float* Wk  = (const float*)d_in[3];
  const float* Wv  = (const float*)d_in[4];
  const float* Wo  = (const float*)d_in[5];
  const float* bo  = (const float*)d_in[6];
  char* ws = (char*)d_ws;

  // po (16 MB) aliases xb+cb (dead after qkv_gemm, before flash_attn writes po)
  unsigned short* xb   = (unsigned short*)(ws);              // 8 MB
  unsigned short* cb   = (unsigned short*)(ws + 8388608);    // 8 MB
  unsigned short* po   = (unsigned short*)(ws);              // 16 MB, [half][bh][q][64]
  unsigned short* wqt  = (unsigned short*)(ws + 16777216);   // 512 KB each
  unsigned short* wkt  = (unsigned short*)(ws + 17301504);
  unsigned short* wvt  = (unsigned short*)(ws + 17825792);
  unsigned short* wot  = (unsigned short*)(ws + 18350080);
  unsigned short* q_ws = (unsigned short*)(ws + 18874368);   // 8 MB, [bh][n][64]
  unsigned short* k_ws = (unsigned short*)(ws + 27262976);   // 8 MB, [bh][m][64]
  unsigned short* v_ws = (unsigned short*)(ws + 35651584);   // 8 MB, [bh][64][m]
  float*          pml  = (float*)(ws + 44040192);            // 512 KB, [half][bh*2048+q]
  float* out = (float*)d_out;

  cvt_inputs<<<4096, 256, 0, stream>>>(x, ctx, xb, cb);
  cvt_weights<<<dim3(16, 16, 4), dim3(32, 8), 0, stream>>>(Wq, Wk, Wv, Wo, wqt, wkt, wvt, wot);

  qkv_gemm<<<dim3(64, 4, 3), 256, 0, stream>>>(xb, cb, wqt, wkt, wvt, q_ws, k_ws, v_ws);

  flash_attn<<<dim3(32, 8, 2), 256, 0, stream>>>(q_ws, k_ws, v_ws, po, pml);

  out_gemm<<<dim3(64, 8), 256, 0, stream>>>(po, pml, wot, out, bo);
}

// Round 10
// 95.377 us; speedup vs baseline: 1.2145x; 1.0424x over previous
//
#include <hip/hip_runtime.h>

// CrossAttention: x[4,2048,512], context[4,2048,512], Wq/Wk/Wv[512,512], Wo[512,512], bo[512]
// out = softmax(QK^T/sqrt(64)) V -> @Wo + bo.  All-bf16 MFMA pipeline, fp32 accum.
// R10: T2 XOR-swizzle on qkv_gemm + out_gemm LDS tiles (R9 audit: their MFMA-operand
//      ds_read_b128 were 16-way bank-conflicted, 4.7M conflicts/dispatch — row-stride
//      128B puts every row's slot s in the same banks). flash reverted to R8 8-wave.

typedef short bf16x8 __attribute__((ext_vector_type(8)));
typedef float f32x4 __attribute__((ext_vector_type(4)));
typedef float f32x16 __attribute__((ext_vector_type(16)));
typedef unsigned int u32x4 __attribute__((ext_vector_type(4)));
typedef unsigned short u16x8 __attribute__((ext_vector_type(8)));

#define NB 4
#define NN 2048
#define QD 512
#define DH 64
// log2(e)/sqrt(DH): folded into Q so softmax runs in exp2 domain
#define QSCALE 0.18033688011112042f

__device__ __forceinline__ unsigned short f2bf(float f) {
  unsigned u = __float_as_uint(f);
  unsigned r = (u + 0x7fffu + ((u >> 16) & 1u)) >> 16;
  return (unsigned short)r;
}

__device__ __forceinline__ unsigned cvtpk(float a, float b) {
  unsigned r;
  asm("v_cvt_pk_bf16_f32 %0, %1, %2" : "=v"(r) : "v"(a), "v"(b));
  return r;
}

__device__ __forceinline__ void pl32swap(unsigned& a, unsigned& b) {
  asm("v_permlane32_swap_b32 %0, %1" : "+v"(a), "+v"(b));
}

__device__ __forceinline__ void gload16(const void* g, void* l) {
  __builtin_amdgcn_global_load_lds((const __attribute__((address_space(1))) unsigned int*)g,
                                   (__attribute__((address_space(3))) unsigned int*)l, 16, 0, 0);
}

// ---------------- convert x / context to bf16 ----------------
__global__ __launch_bounds__(256) void cvt_inputs(const float* __restrict__ x,
                                                  const float* __restrict__ ctx,
                                                  unsigned short* __restrict__ xb,
                                                  unsigned short* __restrict__ cb) {
  int i = blockIdx.x * 256 + threadIdx.x;
  const int total = (NB * NN * QD) / 4;
  if (i < total) {
    float4 v = ((const float4*)x)[i];
    ushort4 o;
    o.x = f2bf(v.x); o.y = f2bf(v.y); o.z = f2bf(v.z); o.w = f2bf(v.w);
    ((ushort4*)xb)[i] = o;
    float4 w = ((const float4*)ctx)[i];
    ushort4 p;
    p.x = f2bf(w.x); p.y = f2bf(w.y); p.z = f2bf(w.z); p.w = f2bf(w.w);
    ((ushort4*)cb)[i] = p;
  }
}

// ---------------- transpose weights to [col][k] bf16 ----------------
__global__ __launch_bounds__(256) void cvt_weights(const float* __restrict__ Wq, const float* __restrict__ Wk,
                                                   const float* __restrict__ Wv, const float* __restrict__ Wo,
                                                   unsigned short* __restrict__ wqt, unsigned short* __restrict__ wkt,
                                                   unsigned short* __restrict__ wvt, unsigned short* __restrict__ wot) {
  __shared__ float t[32][33];
  const float* W = blockIdx.z == 0 ? Wq : blockIdx.z == 1 ? Wk : blockIdx.z == 2 ? Wv : Wo;
  unsigned short* O = blockIdx.z == 0 ? wqt : blockIdx.z == 1 ? wkt : blockIdx.z == 2 ? wvt : wot;
  int c0 = blockIdx.x * 32, k0 = blockIdx.y * 32;
  int tx = threadIdx.x, ty = threadIdx.y;  // 32 x 8
#pragma unroll
  for (int j = 0; j < 4; j++) t[ty + 8 * j][tx] = W[(k0 + ty + 8 * j) * QD + c0 + tx];
  __syncthreads();
#pragma unroll
  for (int j = 0; j < 4; j++) O[(c0 + ty + 8 * j) * QD + k0 + tx] = f2bf(t[tx][ty + 8 * j]);
}

// ---------------- fused QKV projection: gload dbuf + XOR swizzle + LDS-bounce V^T ----------------
// grid (64 rowblk, 4 colblk, 3 z). 128x128 tile, BK=64, 4 waves (2x2). LDS 64 KB.
// Both-sides swizzle (rule #21): LDS[row][s] holds global slot s^(row&7); reads XOR back.
__global__ __launch_bounds__(256, 2) void qkv_gemm(const unsigned short* __restrict__ xb,
                                                   const unsigned short* __restrict__ cb,
                                                   const unsigned short* __restrict__ wqt,
                                                   const unsigned short* __restrict__ wkt,
                                                   const unsigned short* __restrict__ wvt,
                                                   unsigned short* __restrict__ q_ws,
                                                   unsigned short* __restrict__ k_ws,
                                                   unsigned short* __restrict__ v_ws) {
  __shared__ __align__(16) char sAB[2][32768];  // [buf][A 128x64 | B 128x64]; reused as bounce
  const int z = blockIdx.z;
  const unsigned short* A = (z == 0) ? xb : cb;
  const unsigned short* Bt = (z == 0) ? wqt : (z == 1) ? wkt : wvt;
  const int lane = threadIdx.x & 63, wid = threadIdx.x >> 6;
  const int lo = lane & 15, hi = lane >> 4;
  const int wm = wid >> 1, wn = wid & 1;
  const int r0 = blockIdx.x * 128, c0 = blockIdx.y * 128;
  const int r8 = lane >> 3, c8l = lane & 7;

#define STAGEQ(K0, BUF)                                                          \
  do {                                                                           \
    char* b_ = sAB[BUF];                                                         \
    _Pragma("unroll") for (int i_ = 0; i_ < 4; ++i_) {                           \
      int chunk_ = wid * 4 + i_;                                                 \
      int row_ = chunk_ * 8 + r8;                                                \
      int sw_ = (c8l ^ (row_ & 7)) * 8;                                          \
      gload16(&A[(r0 + row_) * QD + (K0) + sw_], b_ + chunk_ * 1024);            \
      gload16(&Bt[(c0 + row_) * QD + (K0) + sw_], b_ + 16384 + chunk_ * 1024);   \
    }                                                                            \
  } while (0)

  f32x4 acc[4][4] = {};
  STAGEQ(0, 0);
  for (int ks = 0; ks < 8; ++ks) {
    asm volatile("s_waitcnt vmcnt(0)" ::: "memory");  // own stage(ks) writes landed
    __builtin_amdgcn_s_barrier();                      // all stage(ks) done; buf(ks^1) consumed
    __builtin_amdgcn_sched_barrier(0);
    if (ks + 1 < 8) STAGEQ((ks + 1) * 64, (ks + 1) & 1);
    const unsigned short* sA = (const unsigned short*)sAB[ks & 1];
    const unsigned short* sB = sA + 8192;
#pragma unroll
    for (int kk = 0; kk < 2; kk++) {
      bf16x8 af[4], bfr[4];
#pragma unroll
      for (int t = 0; t < 4; t++) {
        int row = wm * 64 + t * 16 + lo;
        af[t] = *(const bf16x8*)&sA[row * 64 + ((kk * 4 + hi) ^ (row & 7)) * 8];
      }
#pragma unroll
      for (int u = 0; u < 4; u++) {
        int row = wn * 64 + u * 16 + lo;
        bfr[u] = *(const bf16x8*)&sB[row * 64 + ((kk * 4 + hi) ^ (row & 7)) * 8];
      }
#pragma unroll
      for (int t = 0; t < 4; t++)
#pragma unroll
        for (int u = 0; u < 4; u++)
          acc[t][u] = __builtin_amdgcn_mfma_f32_16x16x32_bf16(af[t], bfr[u], acc[t][u], 0, 0, 0);
    }
  }
#undef STAGEQ

  if (z == 2) {
    // V^T epilogue: bounce through LDS [128 hd][136 m] (pad 8), coalesced 16B stores.
    __syncthreads();  // k-loop LDS reads done before overwrite
    unsigned short* tb = (unsigned short*)sAB;
#pragma unroll
    for (int t = 0; t < 4; t++)
#pragma unroll
      for (int u = 0; u < 4; u++)
#pragma unroll
        for (int ri = 0; ri < 4; ri++) {
          int rloc = wm * 64 + t * 16 + hi * 4 + ri;   // m within tile
          int cloc = wn * 64 + u * 16 + lo;            // hd within tile
          tb[cloc * 136 + rloc] = f2bf(acc[t][u][ri]);
        }
    __syncthreads();
    const int b = r0 >> 11, n0 = r0 & 2047;
#pragma unroll
    for (int i = 0; i < 8; i++) {
      int hd = i * 16 + (threadIdx.x >> 4);
      int mcol = (threadIdx.x & 15) * 8;
      u16x8 v = *(const u16x8*)&tb[hd * 136 + mcol];
      int h = (c0 + hd) >> 6, d = (c0 + hd) & 63;
      *(u16x8*)&v_ws[(((b << 3) | h) * DH + d) * NN + n0 + mcol] = v;
    }
  } else {
    const float outscale = (z == 0) ? QSCALE : 1.0f;
    unsigned short* Cq = (z == 0) ? q_ws : k_ws;
#pragma unroll
    for (int t = 0; t < 4; t++)
#pragma unroll
      for (int u = 0; u < 4; u++)
#pragma unroll
        for (int ri = 0; ri < 4; ri++) {
          int r = r0 + wm * 64 + t * 16 + hi * 4 + ri;
          int c = c0 + wn * 64 + u * 16 + lo;
          float v = acc[t][u][ri] * outscale;
          int b = r >> 11, n = r & 2047, h = c >> 6, d = c & 63;
          Cq[(((b << 3) | h) * NN + n) * DH + d] = f2bf(v);
        }
  }
}

// ---------------- flash attention: 8-wave, KVBLK=64, fixed-max, split-KV (R8, proven) ----------------
__global__ __launch_bounds__(512, 4) void flash_attn(const unsigned short* __restrict__ Q,
                                                     const unsigned short* __restrict__ K,
                                                     const unsigned short* __restrict__ Vt,
                                                     unsigned short* __restrict__ po,
                                                     float* __restrict__ pml) {
  __shared__ __align__(16) char sKV[2][16384];  // [buf][K 64x64 | V^T 64x64]
  const int tid = threadIdx.x;
  const int lane = tid & 63, wid = tid >> 6;
  const int l31 = lane & 31, hi = lane >> 5;
  const int bh = blockIdx.x, half = blockIdx.z;
  const int bhK = bh * NN, bhV = bh * DH;
  const int kv0 = half * (NN / 2);
  const int qrow = blockIdx.y * 256 + wid * 32 + l31;
  po += half * (32 * 2048 * 64);
  pml += half * (32 * 2048);

  // Q fragments (B-operand): col=q(=l31), k(d) = ks*16 + hi*8 + j
  bf16x8 qf[4];
#pragma unroll
  for (int ks = 0; ks < 4; ks++)
    qf[ks] = *(const bf16x8*)&Q[(bhK + qrow) * DH + ks * 16 + hi * 8];

  // staging role: thread t handles chunk t of K region and chunk t of V region
  const int row_s = tid >> 3, slot_s = tid & 7;
  const int swz = (slot_s ^ (row_s & 7)) * 8;

#define STAGE(J0, BUF)                                                     \
  do {                                                                     \
    char* b_ = (char*)sKV[BUF];                                            \
    gload16(&K[(bhK + (J0) + row_s) * DH + swz], b_ + wid * 1024);         \
    gload16(&Vt[(bhV + row_s) * NN + (J0) + swz], b_ + 8192 + wid * 1024); \
  } while (0)

  float l = 0.f;
  f32x16 o[2] = {};

  STAGE(kv0, 0);

  for (int it = 0; it < 16; ++it) {
    asm volatile("s_waitcnt vmcnt(0)" ::: "memory");  // own stage(it) writes done
    __builtin_amdgcn_s_barrier();                      // all stage(it) done; buf(it+1) consumed
    __builtin_amdgcn_sched_barrier(0);
    if (it + 1 < 16) STAGE(kv0 + (it + 1) * 64, (it + 1) & 1);
    const char* buf = (const char*)sKV[it & 1];

    // S^T[key][q] = K . Q^T  (2 key-tiles of 32, 4 d-slices of 16)
    f32x16 st[2] = {};
    __builtin_amdgcn_s_setprio(1);
#pragma unroll
    for (int g = 0; g < 2; g++)
#pragma unroll
      for (int ks = 0; ks < 4; ks++) {
        bf16x8 kf = *(const bf16x8*)(buf + (g * 32 + l31) * 128 + (((ks * 2 + hi) ^ (l31 & 7)) << 4));
        st[g] = __builtin_amdgcn_mfma_f32_32x32x16_bf16(kf, qf[ks], st[g], 0, 0, 0);
      }
    __builtin_amdgcn_s_setprio(0);

    // fixed-max softmax (m = 0; shift-invariant, logits hard-bounded far below fp32 overflow)
#pragma unroll
    for (int g = 0; g < 2; g++)
#pragma unroll
      for (int c = 0; c < 16; c++) st[g][c] = __builtin_amdgcn_exp2f(st[g][c]);
    float s8[8];
#pragma unroll
    for (int c = 0; c < 8; c++) s8[c] = (st[0][c] + st[0][c + 8]) + (st[1][c] + st[1][c + 8]);
#pragma unroll
    for (int w = 4; w >= 1; w >>= 1)
#pragma unroll
      for (int c = 0; c < 4; c++)
        if (c < w) s8[c] += s8[c + w];
    l += s8[0] + __shfl_xor(s8[0], 32);

    // P -> bf16 B-fragments (verified mapping):
    // (w0,w2)=swap(pk(c0,c1),pk(c4,c5)); (w1,w3)=swap(pk(c2,c3),pk(c6,c7)); cb=s*8.
    bf16x8 pf[2][2];
#pragma unroll
    for (int g = 0; g < 2; g++)
#pragma unroll
      for (int s = 0; s < 2; s++) {
        const int cb = s * 8;
        unsigned a0 = cvtpk(st[g][cb + 0], st[g][cb + 1]);
        unsigned a1 = cvtpk(st[g][cb + 2], st[g][cb + 3]);
        unsigned b0 = cvtpk(st[g][cb + 4], st[g][cb + 5]);
        unsigned b1 = cvtpk(st[g][cb + 6], st[g][cb + 7]);
        pl32swap(a0, b0);
        pl32swap(a1, b1);
        union { unsigned u[4]; bf16x8 v; } pu;
        pu.u[0] = a0; pu.u[1] = a1; pu.u[2] = b0; pu.u[3] = b1;
        pf[g][s] = pu.v;
      }

    // O^T[d][q] += V^T . P^T  (2 d-tiles x 2 key-tiles x 2 slices)
    __builtin_amdgcn_s_setprio(1);
#pragma unroll
    for (int dt = 0; dt < 2; dt++)
#pragma unroll
      for (int g = 0; g < 2; g++)
#pragma unroll
        for (int s = 0; s < 2; s++) {
          int row = dt * 32 + l31;
          bf16x8 vf = *(const bf16x8*)(buf + 8192 + row * 128 + (((g * 4 + s * 2 + hi) ^ (row & 7)) << 4));
          o[dt] = __builtin_amdgcn_mfma_f32_32x32x16_bf16(vf, pf[g][s], o[dt], 0, 0, 0);
        }
    __builtin_amdgcn_s_setprio(0);
  }
#undef STAGE

  // store partial: o normalized by own l (bf16); l (f32)
  float inv = 1.f / l;
  const int rbase = (bh * 2048 + qrow) * 64;
#pragma unroll
  for (int dt = 0; dt < 2; dt++)
#pragma unroll
    for (int cg = 0; cg < 4; cg++) {
      ushort4 w;
      w.x = f2bf(o[dt][cg * 4 + 0] * inv);
      w.y = f2bf(o[dt][cg * 4 + 1] * inv);
      w.z = f2bf(o[dt][cg * 4 + 2] * inv);
      w.w = f2bf(o[dt][cg * 4 + 3] * inv);
      int d0 = dt * 32 + cg * 8 + hi * 4;
      *(ushort4*)&po[rbase + d0] = w;
    }
  if (hi == 0) pml[bh * 2048 + qrow] = l;
}

// ---------------- output projection with fused split-KV combine + XOR swizzle ----------------
__global__ __launch_bounds__(256, 2) void out_gemm(const unsigned short* __restrict__ po,
                                                   const float* __restrict__ pml,
                                                   const unsigned short* __restrict__ Bt,
                                                   float* __restrict__ out,
                                                   const float* __restrict__ bias) {
  __shared__ __align__(16) unsigned short sA[128 * 64];
  __shared__ __align__(16) unsigned short sB[64 * 64];
  const unsigned short* po1 = po + 32 * 2048 * 64;
  const float* pml1 = pml + 32 * 2048;
  const int lane = threadIdx.x & 63, wid = threadIdx.x >> 6;
  const int lo = lane & 15, hi = lane >> 4;
  const int wm = wid >> 1, wn = wid & 1;
  const int r0 = blockIdx.x * 128, c0 = blockIdx.y * 64;
  const int r8 = lane >> 3, c8l = lane & 7;
  f32x4 acc[4][2] = {};
  for (int k0 = 0; k0 < QD; k0 += 64) {
    __syncthreads();
    const int h = k0 >> 6;
#pragma unroll
    for (int i = 0; i < 4; i++) {
      int id = i * 256 + threadIdx.x;
      int row = id >> 3, slot = id & 7;
      int r = r0 + row, b = r >> 11, n = r & 2047;
      int pr = ((b << 3) | h) * NN + n;
      float la = pml[pr], lb = pml1[pr];
      float s = __builtin_amdgcn_rcpf(la + lb);
      float wa = la * s, wb = lb * s;
      u32x4 A0 = *(const u32x4*)&po[pr * 64 + slot * 8];
      u32x4 A1 = *(const u32x4*)&po1[pr * 64 + slot * 8];
      u32x4 res;
#pragma unroll
      for (int j = 0; j < 4; j++) {
        float a_lo = __uint_as_float(A0[j] << 16), a_hi = __uint_as_float(A0[j] & 0xffff0000u);
        float b_lo = __uint_as_float(A1[j] << 16), b_hi = __uint_as_float(A1[j] & 0xffff0000u);
        res[j] = cvtpk(a_lo * wa + b_lo * wb, a_hi * wa + b_hi * wb);
      }
      // swizzled write: LDS[row][slot ^ (row&7)] = global slot `slot`
      int swid = (id & ~7) | (slot ^ (row & 7));
      *(u32x4*)((char*)sA + swid * 16) = res;
    }
#pragma unroll
    for (int i = 0; i < 2; i++) {
      int chunk = wid * 2 + i;
      int row = chunk * 8 + r8;
      gload16(&Bt[(c0 + row) * QD + k0 + ((c8l ^ (row & 7)) * 8)], (char*)sB + chunk * 1024);
    }
    __syncthreads();
#pragma unroll
    for (int kk = 0; kk < 2; kk++) {
      bf16x8 af[4], bfr[2];
#pragma unroll
      for (int t = 0; t < 4; t++) {
        int row = wm * 64 + t * 16 + lo;
        af[t] = *(const bf16x8*)&sA[row * 64 + ((kk * 4 + hi) ^ (row & 7)) * 8];
      }
#pragma unroll
      for (int u = 0; u < 2; u++) {
        int row = wn * 32 + u * 16 + lo;
        bfr[u] = *(const bf16x8*)&sB[row * 64 + ((kk * 4 + hi) ^ (row & 7)) * 8];
      }
#pragma unroll
      for (int t = 0; t < 4; t++)
#pragma unroll
        for (int u = 0; u < 2; u++)
          acc[t][u] = __builtin_amdgcn_mfma_f32_16x16x32_bf16(af[t], bfr[u], acc[t][u], 0, 0, 0);
    }
  }
#pragma unroll
  for (int t = 0; t < 4; t++)
#pragma unroll
    for (int u = 0; u < 2; u++)
#pragma unroll
      for (int ri = 0; ri < 4; ri++) {
        int r = r0 + wm * 64 + t * 16 + hi * 4 + ri;
        int c = c0 + wn * 32 + u * 16 + lo;
        out[r * QD + c] = acc[t][u][ri] + bias[c];
      }
}

extern "C" void kernel_launch(void* const* d_in, const int* in_sizes, int n_in,
                              void* d_out, int out_size, void* d_ws, size_t ws_size,
                              hipStream_t stream) {
  const float* x   = (const float*)d_in[0];
  const float* ctx = (const float*)d_in[1];
  const float* Wq  = (const float*)d_in[2];
  const float* Wk  = (const float*)d_in[3];
  const float* Wv  = (const float*)d_in[4];
  const float* Wo  = (const float*)d_in[5];
  const float* bo  = (const float*)d_in[6];
  char* ws = (char*)d_ws;

  // po (16 MB) aliases xb+cb (dead after qkv_gemm, before flash_attn writes po)
  unsigned short* xb   = (unsigned short*)(ws);              // 8 MB
  unsigned short* cb   = (unsigned short*)(ws + 8388608);    // 8 MB
  unsigned short* po   = (unsigned short*)(ws);              // 16 MB, [half][bh][q][64]
  unsigned short* wqt  = (unsigned short*)(ws + 16777216);   // 512 KB each
  unsigned short* wkt  = (unsigned short*)(ws + 17301504);
  unsigned short* wvt  = (unsigned short*)(ws + 17825792);
  unsigned short* wot  = (unsigned short*)(ws + 18350080);
  unsigned short* q_ws = (unsigned short*)(ws + 18874368);   // 8 MB, [bh][n][64]
  unsigned short* k_ws = (unsigned short*)(ws + 27262976);   // 8 MB, [bh][m][64]
  unsigned short* v_ws = (unsigned short*)(ws + 35651584);   // 8 MB, [bh][64][m]
  float*          pml  = (float*)(ws + 44040192);            // 512 KB, [half][bh*2048+q]
  float* out = (float*)d_out;

  cvt_inputs<<<4096, 256, 0, stream>>>(x, ctx, xb, cb);
  cvt_weights<<<dim3(16, 16, 4), dim3(32, 8), 0, stream>>>(Wq, Wk, Wv, Wo, wqt, wkt, wvt, wot);

  qkv_gemm<<<dim3(64, 4, 3), 256, 0, stream>>>(xb, cb, wqt, wkt, wvt, q_ws, k_ws, v_ws);

  flash_attn<<<dim3(32, 8, 2), 512, 0, stream>>>(q_ws, k_ws, v_ws, po, pml);

  out_gemm<<<dim3(64, 8), 256, 0, stream>>>(po, pml, wot, out, bo);
}